// Round 3
// baseline (288.257 us; speedup 1.0000x reference)
//
#include <hip/hip_runtime.h>
#include <hip/hip_bf16.h>

typedef __attribute__((ext_vector_type(8))) _Float16 half8;   // 8 f16 = 4 VGPRs
typedef __attribute__((ext_vector_type(4))) float f32x4;

#define MFMAH(a, b, c) __builtin_amdgcn_mfma_f32_16x16x32_f16((a), (b), (c), 0, 0, 0)

__device__ __forceinline__ short f2h(float v) { _Float16 h = (_Float16)v; return __builtin_bit_cast(short, h); }
__device__ __forceinline__ float h2f(short s) { return (float)__builtin_bit_cast(_Float16, s); }
__device__ __forceinline__ f32x4 fzero() { f32x4 z = {0.f, 0.f, 0.f, 0.f}; return z; }

__device__ __forceinline__ float gelu_tanh(float v) {
    // jax.nn.gelu default (approximate=True)
    float u = 0.7978845608028654f * (v + 0.044715f * v * v * v);
    return 0.5f * v * (1.f + tanhf(u));
}

// ---------------- prep kernels (fp32 -> fp16 containers as short) ----------------

// W_off2 (256,4096) fp32 -> B2T (4096,768) f16, row n = [w1T | w1T | w2T]
__global__ void split_w2_k(const float* __restrict__ w, short* __restrict__ dst) {
    int i = blockIdx.x * 256 + threadIdx.x;        // 4096*256
    int n = i >> 8, k = i & 255;
    float v = w[(long)k * 4096 + n];
    _Float16 w1 = (_Float16)v;
    _Float16 w2 = (_Float16)(v - (float)w1);
    dst[n * 768 + k]       = __builtin_bit_cast(short, w1);
    dst[n * 768 + 256 + k] = __builtin_bit_cast(short, w1);
    dst[n * 768 + 512 + k] = __builtin_bit_cast(short, w2);
}

// Wq,Wk,Wv (256,256) fp32 -> (768,256) f16 rows: [Wq^T; Wk^T; Wv^T]
__global__ void qkv_prep_k(const float* __restrict__ Wq, const float* __restrict__ Wk,
                           const float* __restrict__ Wv, short* __restrict__ dst) {
    int i = blockIdx.x * 256 + threadIdx.x;        // 768*256
    int n = i >> 8, k = i & 255;
    const float* s = (n < 256) ? Wq : (n < 512) ? Wk : Wv;
    dst[i] = f2h(s[k * 256 + (n & 255)]);
}

// Wo (2048,256) fp32 -> (256,2048) f16 transposed
__global__ void wo_prep_k(const float* __restrict__ Wo, short* __restrict__ dst) {
    int i = blockIdx.x * 256 + threadIdx.x;        // 256*2048
    int n = i >> 11, k = i & 2047;
    dst[i] = f2h(Wo[k * 256 + n]);
}

// ---------------- GEMM1: exact fp32, fused gelu + fp16 hi/lo split ----------------
// h = gelu(x(2048,256) @ W1(256,256) + b1) -> hsplit (2048,768) f16 [h1 | h2 | h1]

__global__ __launch_bounds__(256) void gemm1_k(const float* __restrict__ x, const float* __restrict__ W,
                                               const float* __restrict__ bias, short* __restrict__ hs) {
    __shared__ float As[64][17];
    __shared__ float Bs[16][68];
    const int tid = threadIdx.x;
    const int bm = blockIdx.x >> 2, bn = blockIdx.x & 3;     // 32 x 4
    const int m0 = bm * 64, n0 = bn * 64;
    const int ty = tid >> 4, tx = tid & 15;
    float acc[4][4] = {};
    const int ar = tid >> 2, ak = (tid & 3) << 2;
    const int bk = tid >> 4, bc = (tid & 15) << 2;

    for (int k0 = 0; k0 < 256; k0 += 16) {
        __syncthreads();
        float4 av = *(const float4*)(x + (m0 + ar) * 256 + k0 + ak);
        As[ar][ak + 0] = av.x; As[ar][ak + 1] = av.y; As[ar][ak + 2] = av.z; As[ar][ak + 3] = av.w;
        *(float4*)&Bs[bk][bc] = *(const float4*)(W + (k0 + bk) * 256 + n0 + bc);
        __syncthreads();
#pragma unroll
        for (int kk = 0; kk < 16; ++kk) {
            float a_[4], b_[4];
#pragma unroll
            for (int i = 0; i < 4; ++i) a_[i] = As[ty * 4 + i][kk];
            *(float4*)b_ = *(const float4*)&Bs[kk][tx * 4];
#pragma unroll
            for (int i = 0; i < 4; ++i)
#pragma unroll
                for (int j = 0; j < 4; ++j) acc[i][j] += a_[i] * b_[j];
        }
    }
#pragma unroll
    for (int i = 0; i < 4; ++i) {
        int row = m0 + ty * 4 + i;
#pragma unroll
        for (int j = 0; j < 4; ++j) {
            int col = n0 + tx * 4 + j;
            float v = gelu_tanh(acc[i][j] + bias[col]);
            _Float16 h1 = (_Float16)v;
            _Float16 h2 = (_Float16)(v - (float)h1);
            hs[row * 768 + col]       = __builtin_bit_cast(short, h1);
            hs[row * 768 + 256 + col] = __builtin_bit_cast(short, h2);
            hs[row * 768 + 512 + col] = __builtin_bit_cast(short, h1);
        }
    }
}

// ---------------- generic f16 MFMA GEMM: C = A(M,K) * BT(N,K)^T ----------------
// 4 waves, 64x64 tile, BK=32.
// EPI 1: +bias, tanh -> fused bilinear grid-sample of xsrc -> out0 = xs f16
// EPI 2: qkv scatter (out0=q, out1=k, out2=vT; b0/b1/b2 = bq/bk/bv fp32)
// EPI 3: +bias, fp32 out (out0, ld 256)

template <int EPI>
__global__ __launch_bounds__(256, 2) void gemm_bt(
    const short* __restrict__ A, const short* __restrict__ BT,
    const float* __restrict__ b0, const float* __restrict__ b1, const float* __restrict__ b2,
    void* __restrict__ out0, void* __restrict__ out1, void* __restrict__ out2,
    int M, int N, int K, const float* __restrict__ xsrc)
{
    __shared__ short As[64][40];   // +8 pad, keeps 16B alignment
    __shared__ short Bs[64][40];

    const int tid = threadIdx.x;
    const int lane = tid & 63, wv = tid >> 6;
    const int rl = lane & 15, g = lane >> 4;
    const int nb = N >> 6;
    const int bm = blockIdx.x / nb, bn = blockIdx.x % nb;
    const long m0 = (long)bm * 64, n0 = (long)bn * 64;

    f32x4 acc[4];
#pragma unroll
    for (int nt = 0; nt < 4; ++nt) acc[nt] = fzero();

    const int srow = tid >> 2, scol = (tid & 3) << 3;
    const short* ap = A + (m0 + srow) * K + scol;
    const short* bp = BT + (n0 + srow) * K + scol;

    for (int k0 = 0; k0 < K; k0 += 32) {
        __syncthreads();
        *(half8*)&As[srow][scol] = *(const half8*)(ap + k0);
        *(half8*)&Bs[srow][scol] = *(const half8*)(bp + k0);
        __syncthreads();
        half8 af = *(const half8*)&As[wv * 16 + rl][g * 8];
#pragma unroll
        for (int nt = 0; nt < 4; ++nt) {
            half8 bfv = *(const half8*)&Bs[nt * 16 + rl][g * 8];
            acc[nt] = MFMAH(af, bfv, acc[nt]);
        }
    }

#pragma unroll
    for (int nt = 0; nt < 4; ++nt) {
        long gcol = n0 + nt * 16 + rl;
#pragma unroll
        for (int j = 0; j < 4; ++j) {
            long grow = m0 + wv * 16 + g * 4 + j;
            if (EPI == 1) {
                float o = tanhf(acc[nt][j] + b0[gcol]);
                float po = __shfl_xor(o, 1);
                if ((rl & 1) == 0) {
                    // even col: o = x coord (width, C=256); partner = y (height, DH*T=8192)
                    float gx = (o + 1.f) * 127.5f;
                    float gy = (po + 1.f) * 4095.5f;
                    float x0f = floorf(gx), y0f = floorf(gy);
                    float wx = gx - x0f, wy = gy - y0f;
                    int ix0 = (int)x0f, iy0 = (int)y0f;
                    int ix1 = min(ix0 + 1, 255), iy1 = min(iy0 + 1, 8191);
                    ix0 = max(min(ix0, 255), 0);
                    iy0 = max(min(iy0, 8191), 0);
                    ix1 = max(ix1, 0);
                    iy1 = max(iy1, 0);
                    int n_ = (int)gcol;
                    int c = (n_ >> 1) & 255, d = n_ >> 9;
                    int b = (int)(grow >> 10), t = (int)(grow & 1023);
                    const float* xb = xsrc + b * 262144;
                    int r0 = (iy0 & 1023) << 8, r1 = (iy1 & 1023) << 8;
                    float v00 = xb[r0 + ix0], v01 = xb[r0 + ix1];
                    float v10 = xb[r1 + ix0], v11 = xb[r1 + ix1];
                    float r = v00 * (1.f - wy) * (1.f - wx) + v01 * (1.f - wy) * wx
                            + v10 * wy * (1.f - wx) + v11 * wy * wx;
                    ((short*)out0)[((b * 8 + d) * 1024 + t) * 256 + c] = f2h(r);
                }
            } else if (EPI == 2) {
                int n = (int)gcol;
                if (n < 256) {
                    ((short*)out0)[grow * 256 + n] = f2h(acc[nt][j] + b0[n]);
                } else if (n < 512) {
                    ((short*)out1)[grow * 256 + (n - 256)] = f2h(acc[nt][j] + b1[n - 256]);
                } else {
                    int np = n - 512, hh = np >> 6, dd = np & 63;
                    long bh = grow >> 10, t = grow & 1023;
                    ((short*)out2)[((bh * 4 + hh) * 64 + dd) * 1024 + t] = f2h(acc[nt][j] + b2[np]);
                }
            } else {
                ((float*)out0)[grow * 256 + gcol] = acc[nt][j] + b0[gcol];
            }
        }
    }
}

// ---------------- flash attention: per-wave 16 q-rows, 32-key chunks ----------------
// scores C-layout: col(key)=lane&15, row(q)=(lane>>4)*4+j. P goes through per-wave LDS
// to re-shape into the PV A-fragment (lane&15 = q-row, 8 contiguous keys per lane).

__global__ __launch_bounds__(256) void attn_k(const short* __restrict__ q, const short* __restrict__ km,
                                              const short* __restrict__ vT, short* __restrict__ oc) {
    __shared__ short Pl[4][16][40];
    const int lane = threadIdx.x & 63, wv = threadIdx.x >> 6;
    const int rl = lane & 15, g = lane >> 4;
    const int bhh = blockIdx.x >> 4;          // bh*4 + h
    const int bh = bhh >> 2, h = bhh & 3;
    const int q0 = (blockIdx.x & 15) * 64 + wv * 16;

    const short* qb = q + (long)bh * 1024 * 256 + h * 64;
    const short* kb = km + (long)bh * 1024 * 256 + h * 64;
    const short* vb = vT + (long)(bh * 4 + h) * 64 * 1024;

    half8 aq0 = *(const half8*)(qb + (long)(q0 + rl) * 256 + g * 8);
    half8 aq1 = *(const half8*)(qb + (long)(q0 + rl) * 256 + 32 + g * 8);

    float m_[4] = {-1e30f, -1e30f, -1e30f, -1e30f};
    float l_[4] = {0.f, 0.f, 0.f, 0.f};
    f32x4 O[4];
#pragma unroll
    for (int nt = 0; nt < 4; ++nt) O[nt] = fzero();

    for (int kk = 0; kk < 32; ++kk) {
        const int kbase = kk * 32;
        f32x4 s0 = fzero(), s1 = fzero();
        half8 b00 = *(const half8*)(kb + (long)(kbase + rl) * 256 + g * 8);
        half8 b01 = *(const half8*)(kb + (long)(kbase + 16 + rl) * 256 + g * 8);
        half8 b10 = *(const half8*)(kb + (long)(kbase + rl) * 256 + 32 + g * 8);
        half8 b11 = *(const half8*)(kb + (long)(kbase + 16 + rl) * 256 + 32 + g * 8);
        s0 = MFMAH(aq0, b00, s0); s1 = MFMAH(aq0, b01, s1);
        s0 = MFMAH(aq1, b10, s0); s1 = MFMAH(aq1, b11, s1);

        float p0[4], p1[4], rs[4], mx[4], sc[4];
#pragma unroll
        for (int j = 0; j < 4; ++j) {
            s0[j] *= 0.125f; s1[j] *= 0.125f;
            mx[j] = fmaxf(s0[j], s1[j]);
        }
#pragma unroll
        for (int off = 1; off < 16; off <<= 1)
#pragma unroll
            for (int j = 0; j < 4; ++j) mx[j] = fmaxf(mx[j], __shfl_xor(mx[j], off));
#pragma unroll
        for (int j = 0; j < 4; ++j) {
            float mn = fmaxf(m_[j], mx[j]);
            sc[j] = expf(m_[j] - mn);
            m_[j] = mn;
            p0[j] = expf(s0[j] - mn);
            p1[j] = expf(s1[j] - mn);
            rs[j] = p0[j] + p1[j];
        }
#pragma unroll
        for (int off = 1; off < 16; off <<= 1)
#pragma unroll
            for (int j = 0; j < 4; ++j) rs[j] += __shfl_xor(rs[j], off);
#pragma unroll
        for (int j = 0; j < 4; ++j) l_[j] = l_[j] * sc[j] + rs[j];
#pragma unroll
        for (int nt = 0; nt < 4; ++nt)
#pragma unroll
            for (int j = 0; j < 4; ++j) O[nt][j] *= sc[j];

#pragma unroll
        for (int j = 0; j < 4; ++j) {
            Pl[wv][g * 4 + j][rl]      = f2h(p0[j]);
            Pl[wv][g * 4 + j][16 + rl] = f2h(p1[j]);
        }
        __syncthreads();
        half8 pa = *(const half8*)&Pl[wv][rl][g * 8];
#pragma unroll
        for (int nt = 0; nt < 4; ++nt) {
            half8 vbf = *(const half8*)(vb + (long)(nt * 16 + rl) * 1024 + kbase + g * 8);
            O[nt] = MFMAH(pa, vbf, O[nt]);
        }
        __syncthreads();
    }

    const int b = bh >> 3, d = bh & 7;
    float inv[4];
#pragma unroll
    for (int j = 0; j < 4; ++j) inv[j] = 1.f / l_[j];
#pragma unroll
    for (int nt = 0; nt < 4; ++nt)
#pragma unroll
        for (int j = 0; j < 4; ++j) {
            int t = q0 + g * 4 + j;
            oc[(((long)b * 1024 + t) * 8 + d) * 256 + h * 64 + nt * 16 + rl] = f2h(O[nt][j] * inv[j]);
        }
}

// ---------------- launch ----------------

extern "C" void kernel_launch(void* const* d_in, const int* in_sizes, int n_in,
                              void* d_out, int out_size, void* d_ws, size_t ws_size,
                              hipStream_t stream) {
    const float* x     = (const float*)d_in[0];
    const float* Woff1 = (const float*)d_in[1];
    const float* boff1 = (const float*)d_in[2];
    const float* Woff2 = (const float*)d_in[3];
    const float* boff2 = (const float*)d_in[4];
    const float* Wq    = (const float*)d_in[5];
    const float* bq    = (const float*)d_in[6];
    const float* Wk    = (const float*)d_in[7];
    const float* bk    = (const float*)d_in[8];
    const float* Wv    = (const float*)d_in[9];
    const float* bv    = (const float*)d_in[10];
    const float* Wo    = (const float*)d_in[11];
    const float* bo    = (const float*)d_in[12];

    char* ws = (char*)d_ws;
    // region0: hsplit+B2T (dead after gemm2) -- cat aliases it
    short* hsplit = (short*)(ws + 0);             // 2048*768*2  = 3,145,728
    short* B2T    = (short*)(ws + 3145728);       // 4096*768*2  = 6,291,456 (end 9,437,184)
    short* cat    = (short*)(ws + 0);             // 2048*2048*2 = 8,388,608 (alias)
    short* Wtqkv  = (short*)(ws + 9437184);       // 768*256*2   =   393,216
    short* WtoT   = (short*)(ws + 9830400);       // 256*2048*2  = 1,048,576
    short* xs     = (short*)(ws + 10878976);      // 16384*256*2 = 8,388,608
    short* qbuf   = (short*)(ws + 19267584);      // 8,388,608
    short* kbuf   = (short*)(ws + 27656192);      // 8,388,608
    short* vT     = (short*)(ws + 36044800);      // 8,388,608  (end 44,433,408)

    // prep
    split_w2_k<<<4096, 256, 0, stream>>>(Woff2, B2T);
    qkv_prep_k<<<768, 256, 0, stream>>>(Wq, Wk, Wv, Wtqkv);
    wo_prep_k<<<2048, 256, 0, stream>>>(Wo, WtoT);

    // offset network stage 1: exact fp32 + gelu + fp16 split
    gemm1_k<<<128, 256, 0, stream>>>(x, Woff1, boff1, hsplit);

    // stage 2 (f16 3-term, ~22-bit accurate) + fused tanh + bilinear resampling
    gemm_bt<1><<<(2048 / 64) * (4096 / 64), 256, 0, stream>>>(
        hsplit, B2T, boff2, nullptr, nullptr, xs, nullptr, nullptr, 2048, 4096, 768, x);

    // qkv projections (V written transposed per (bh,h))
    gemm_bt<2><<<(16384 / 64) * (768 / 64), 256, 0, stream>>>(
        xs, Wtqkv, bq, bk, bv, qbuf, kbuf, vT, 16384, 768, 256, nullptr);

    // attention
    attn_k<<<1024, 256, 0, stream>>>(qbuf, kbuf, vT, cat);

    // output projection (fp32 out)
    gemm_bt<3><<<(2048 / 64) * (256 / 64), 256, 0, stream>>>(
        cat, WtoT, bo, nullptr, nullptr, d_out, nullptr, nullptr, 2048, 256, 2048, nullptr);
}

// Round 4
// 226.661 us; speedup vs baseline: 1.2718x; 1.2718x over previous
//
#include <hip/hip_runtime.h>
#include <hip/hip_bf16.h>

typedef __attribute__((ext_vector_type(8))) _Float16 half8;   // 8 f16 = 4 VGPRs
typedef __attribute__((ext_vector_type(4))) float f32x4;
typedef __attribute__((ext_vector_type(16))) float f32x16;
typedef __attribute__((ext_vector_type(2))) unsigned uint2v;
typedef __attribute__((ext_vector_type(4))) unsigned uint4v;

#define MFMAH(a, b, c) __builtin_amdgcn_mfma_f32_16x16x32_f16((a), (b), (c), 0, 0, 0)
#define MFMA32(a, b, c) __builtin_amdgcn_mfma_f32_32x32x16_f16((a), (b), (c), 0, 0, 0)

__device__ __forceinline__ short f2h(float v) { _Float16 h = (_Float16)v; return __builtin_bit_cast(short, h); }
__device__ __forceinline__ f32x4 fzero() { f32x4 z = {0.f, 0.f, 0.f, 0.f}; return z; }

__device__ __forceinline__ float gelu_tanh(float v) {
    // jax.nn.gelu default (approximate=True)
    float u = 0.7978845608028654f * (v + 0.044715f * v * v * v);
    return 0.5f * v * (1.f + tanhf(u));
}

// ---------------- prep kernels (fp32 -> fp16 containers as short) ----------------

// W_off2 (256,4096) fp32 -> B2T (4096,768) f16, row n = [w1T | w1T | w2T]
__global__ void split_w2_k(const float* __restrict__ w, short* __restrict__ dst) {
    int i = blockIdx.x * 256 + threadIdx.x;        // 4096*256
    int n = i >> 8, k = i & 255;
    float v = w[(long)k * 4096 + n];
    _Float16 w1 = (_Float16)v;
    _Float16 w2 = (_Float16)(v - (float)w1);
    dst[n * 768 + k]       = __builtin_bit_cast(short, w1);
    dst[n * 768 + 256 + k] = __builtin_bit_cast(short, w1);
    dst[n * 768 + 512 + k] = __builtin_bit_cast(short, w2);
}

// Wq,Wk,Wv (256,256) fp32 -> (768,256) f16 rows: [Wq^T; Wk^T; Wv^T]
__global__ void qkv_prep_k(const float* __restrict__ Wq, const float* __restrict__ Wk,
                           const float* __restrict__ Wv, short* __restrict__ dst) {
    int i = blockIdx.x * 256 + threadIdx.x;        // 768*256
    int n = i >> 8, k = i & 255;
    const float* s = (n < 256) ? Wq : (n < 512) ? Wk : Wv;
    dst[i] = f2h(s[k * 256 + (n & 255)]);
}

// Wo (2048,256) fp32 -> (256,2048) f16 transposed
__global__ void wo_prep_k(const float* __restrict__ Wo, short* __restrict__ dst) {
    int i = blockIdx.x * 256 + threadIdx.x;        // 256*2048
    int n = i >> 11, k = i & 2047;
    dst[i] = f2h(Wo[k * 256 + n]);
}

// ---------------- GEMM1: exact fp32, fused gelu + fp16 hi/lo split ----------------
// h = gelu(x(2048,256) @ W1(256,256) + b1) -> hsplit (2048,768) f16 [h1 | h2 | h1]

__global__ __launch_bounds__(256) void gemm1_k(const float* __restrict__ x, const float* __restrict__ W,
                                               const float* __restrict__ bias, short* __restrict__ hs) {
    __shared__ float As[64][17];
    __shared__ float Bs[16][68];
    const int tid = threadIdx.x;
    const int bm = blockIdx.x >> 2, bn = blockIdx.x & 3;     // 32 x 4
    const int m0 = bm * 64, n0 = bn * 64;
    const int ty = tid >> 4, tx = tid & 15;
    float acc[4][4] = {};
    const int ar = tid >> 2, ak = (tid & 3) << 2;
    const int bk = tid >> 4, bc = (tid & 15) << 2;

    for (int k0 = 0; k0 < 256; k0 += 16) {
        __syncthreads();
        float4 av = *(const float4*)(x + (m0 + ar) * 256 + k0 + ak);
        As[ar][ak + 0] = av.x; As[ar][ak + 1] = av.y; As[ar][ak + 2] = av.z; As[ar][ak + 3] = av.w;
        *(float4*)&Bs[bk][bc] = *(const float4*)(W + (k0 + bk) * 256 + n0 + bc);
        __syncthreads();
#pragma unroll
        for (int kk = 0; kk < 16; ++kk) {
            float a_[4], b_[4];
#pragma unroll
            for (int i = 0; i < 4; ++i) a_[i] = As[ty * 4 + i][kk];
            *(float4*)b_ = *(const float4*)&Bs[kk][tx * 4];
#pragma unroll
            for (int i = 0; i < 4; ++i)
#pragma unroll
                for (int j = 0; j < 4; ++j) acc[i][j] += a_[i] * b_[j];
        }
    }
#pragma unroll
    for (int i = 0; i < 4; ++i) {
        int row = m0 + ty * 4 + i;
#pragma unroll
        for (int j = 0; j < 4; ++j) {
            int col = n0 + tx * 4 + j;
            float v = gelu_tanh(acc[i][j] + bias[col]);
            _Float16 h1 = (_Float16)v;
            _Float16 h2 = (_Float16)(v - (float)h1);
            hs[row * 768 + col]       = __builtin_bit_cast(short, h1);
            hs[row * 768 + 256 + col] = __builtin_bit_cast(short, h2);
            hs[row * 768 + 512 + col] = __builtin_bit_cast(short, h1);
        }
    }
}

// ---------------- generic f16 MFMA GEMM: C = A(M,K) * BT(N,K)^T ----------------
// 4 waves, 64x64 tile, BK=32.
// EPI 1: +bias, tanh -> fused bilinear grid-sample of xsrc -> out0 = xs f16
// EPI 2: qkv scatter (out0=q scaled by 0.125, out1=k, out2=vT)
// EPI 3: +bias, fp32 out (out0, ld 256)

template <int EPI>
__global__ __launch_bounds__(256, 2) void gemm_bt(
    const short* __restrict__ A, const short* __restrict__ BT,
    const float* __restrict__ b0, const float* __restrict__ b1, const float* __restrict__ b2,
    void* __restrict__ out0, void* __restrict__ out1, void* __restrict__ out2,
    int M, int N, int K, const float* __restrict__ xsrc)
{
    __shared__ short As[64][40];   // +8 pad, keeps 16B alignment
    __shared__ short Bs[64][40];

    const int tid = threadIdx.x;
    const int lane = tid & 63, wv = tid >> 6;
    const int rl = lane & 15, g = lane >> 4;
    const int nb = N >> 6;
    const int bm = blockIdx.x / nb, bn = blockIdx.x % nb;
    const long m0 = (long)bm * 64, n0 = (long)bn * 64;

    f32x4 acc[4];
#pragma unroll
    for (int nt = 0; nt < 4; ++nt) acc[nt] = fzero();

    const int srow = tid >> 2, scol = (tid & 3) << 3;
    const short* ap = A + (m0 + srow) * K + scol;
    const short* bp = BT + (n0 + srow) * K + scol;

    for (int k0 = 0; k0 < K; k0 += 32) {
        __syncthreads();
        *(half8*)&As[srow][scol] = *(const half8*)(ap + k0);
        *(half8*)&Bs[srow][scol] = *(const half8*)(bp + k0);
        __syncthreads();
        half8 af = *(const half8*)&As[wv * 16 + rl][g * 8];
#pragma unroll
        for (int nt = 0; nt < 4; ++nt) {
            half8 bfv = *(const half8*)&Bs[nt * 16 + rl][g * 8];
            acc[nt] = MFMAH(af, bfv, acc[nt]);
        }
    }

#pragma unroll
    for (int nt = 0; nt < 4; ++nt) {
        long gcol = n0 + nt * 16 + rl;
#pragma unroll
        for (int j = 0; j < 4; ++j) {
            long grow = m0 + wv * 16 + g * 4 + j;
            if (EPI == 1) {
                float o = tanhf(acc[nt][j] + b0[gcol]);
                float po = __shfl_xor(o, 1);
                if ((rl & 1) == 0) {
                    // even col: o = x coord (width, C=256); partner = y (height, DH*T=8192)
                    float gx = (o + 1.f) * 127.5f;
                    float gy = (po + 1.f) * 4095.5f;
                    float x0f = floorf(gx), y0f = floorf(gy);
                    float wx = gx - x0f, wy = gy - y0f;
                    int ix0 = (int)x0f, iy0 = (int)y0f;
                    int ix1 = min(ix0 + 1, 255), iy1 = min(iy0 + 1, 8191);
                    ix0 = max(min(ix0, 255), 0);
                    iy0 = max(min(iy0, 8191), 0);
                    ix1 = max(ix1, 0);
                    iy1 = max(iy1, 0);
                    int n_ = (int)gcol;
                    int c = (n_ >> 1) & 255, d = n_ >> 9;
                    int b = (int)(grow >> 10), t = (int)(grow & 1023);
                    const float* xb = xsrc + b * 262144;
                    int r0 = (iy0 & 1023) << 8, r1 = (iy1 & 1023) << 8;
                    float v00 = xb[r0 + ix0], v01 = xb[r0 + ix1];
                    float v10 = xb[r1 + ix0], v11 = xb[r1 + ix1];
                    float r = v00 * (1.f - wy) * (1.f - wx) + v01 * (1.f - wy) * wx
                            + v10 * wy * (1.f - wx) + v11 * wy * wx;
                    ((short*)out0)[((b * 8 + d) * 1024 + t) * 256 + c] = f2h(r);
                }
            } else if (EPI == 2) {
                int n = (int)gcol;
                if (n < 256) {
                    // q scaled by 1/sqrt(HD): folded out of the attention inner loop
                    ((short*)out0)[grow * 256 + n] = f2h((acc[nt][j] + b0[n]) * 0.125f);
                } else if (n < 512) {
                    ((short*)out1)[grow * 256 + (n - 256)] = f2h(acc[nt][j] + b1[n - 256]);
                } else {
                    int np = n - 512, hh = np >> 6, dd = np & 63;
                    long bh = grow >> 10, t = grow & 1023;
                    ((short*)out2)[((bh * 4 + hh) * 64 + dd) * 1024 + t] = f2h(acc[nt][j] + b2[np]);
                }
            } else {
                ((float*)out0)[grow * 256 + gcol] = acc[nt][j] + b0[gcol];
            }
        }
    }
}

// ---------------- flash attention: swapped-operand, 32 q-rows/wave, no LDS ----------------
// S^T = mfma32(K, Q): col(q)=lane&31, row(key)=(reg&3)+8*(reg>>2)+4*(lane>>5).
// Each lane owns one q-row (16 of 32 keys; partner lane^32 has the rest).
// P^T fragment built in-register via cvt_pkrtz + permlane32_swap (T12).
// O^T = mfma32(V^T, P^T): col(q)=lane&31 -> rescale & 1/l are per-lane scalars.

__global__ __launch_bounds__(256) void attn_k(const short* __restrict__ q, const short* __restrict__ km,
                                              const short* __restrict__ vT, short* __restrict__ oc) {
    const int lane = threadIdx.x & 63, wv = threadIdx.x >> 6;
    const int l31 = lane & 31, hi = lane >> 5;
    const int bhh = blockIdx.x >> 3;          // bh*4 + h  (64 combos)
    const int bh = bhh >> 2, h = bhh & 3;
    const int q0 = (blockIdx.x & 7) * 128 + wv * 32;

    const short* qb = q + (long)bh * 262144 + h * 64;
    const short* kb = km + (long)bh * 262144 + h * 64;
    const short* vb = vT + (long)bhh * 65536;

    half8 qf[4];
#pragma unroll
    for (int c = 0; c < 4; ++c)
        qf[c] = *(const half8*)(qb + (long)(q0 + l31) * 256 + c * 16 + hi * 8);

    float m_ = -1e30f, l_ = 0.f;
    f32x16 O0, O1;
#pragma unroll
    for (int r = 0; r < 16; ++r) { O0[r] = 0.f; O1[r] = 0.f; }

    for (int kk = 0; kk < 32; ++kk) {
        const int kbase = kk * 32;
        f32x16 S;
#pragma unroll
        for (int r = 0; r < 16; ++r) S[r] = 0.f;
#pragma unroll
        for (int c = 0; c < 4; ++c) {
            half8 kf = *(const half8*)(kb + (long)(kbase + l31) * 256 + c * 16 + hi * 8);
            S = MFMA32(kf, qf[c], S);
        }
        // row max over 32 keys (16 own + 16 from partner lane^32)
        float mx = S[0];
#pragma unroll
        for (int r = 1; r < 16; ++r) mx = fmaxf(mx, S[r]);
        mx = fmaxf(mx, __shfl_xor(mx, 32));
        if (__any(mx > m_)) {                 // defer-max: rescale only when max grows
            float mn = fmaxf(m_, mx);
            float sc = __expf(m_ - mn);
            m_ = mn;
            l_ *= sc;
#pragma unroll
            for (int r = 0; r < 16; ++r) { O0[r] *= sc; O1[r] *= sc; }
        }
        float p[16];
        float rs = 0.f;
#pragma unroll
        for (int r = 0; r < 16; ++r) { p[r] = __expf(S[r] - m_); rs += p[r]; }
        rs += __shfl_xor(rs, 32);
        l_ += rs;
        // pack P^T fragments: chunk c covers keys [kbase+16c, kbase+16c+16)
        half8 PA[2];
#pragma unroll
        for (int c = 0; c < 2; ++c) {
            const int o = c * 8;
            unsigned a0 = __builtin_bit_cast(unsigned, __builtin_amdgcn_cvt_pkrtz(p[o + 0], p[o + 1]));
            unsigned b0v = __builtin_bit_cast(unsigned, __builtin_amdgcn_cvt_pkrtz(p[o + 4], p[o + 5]));
            unsigned a1 = __builtin_bit_cast(unsigned, __builtin_amdgcn_cvt_pkrtz(p[o + 2], p[o + 3]));
            unsigned b1v = __builtin_bit_cast(unsigned, __builtin_amdgcn_cvt_pkrtz(p[o + 6], p[o + 7]));
            uint2v r0 = __builtin_amdgcn_permlane32_swap(a0, b0v, false, false);
            uint2v r1 = __builtin_amdgcn_permlane32_swap(a1, b1v, false, false);
            uint4v w = {r0[0], r1[0], r0[1], r1[1]};
            PA[c] = __builtin_bit_cast(half8, w);
        }
        // O^T += V^T * P^T
#pragma unroll
        for (int c = 0; c < 2; ++c) {
            half8 v0 = *(const half8*)(vb + (long)l31 * 1024 + kbase + c * 16 + hi * 8);
            half8 v1 = *(const half8*)(vb + (long)(32 + l31) * 1024 + kbase + c * 16 + hi * 8);
            O0 = MFMA32(v0, PA[c], O0);
            O1 = MFMA32(v1, PA[c], O1);
        }
    }

    const float inv = 1.f / l_;
    const int b = bh >> 3, d = bh & 7;
    const int t = q0 + l31;
    short* ob = oc + ((long)(b * 1024 + t) * 8 + d) * 256 + h * 64;
#pragma unroll
    for (int rr = 0; rr < 8; ++rr) {
        int dvb = (rr & 1) * 2 + 8 * (rr >> 1) + 4 * hi;
        unsigned u0 = (unsigned short)f2h(O0[2 * rr] * inv) | ((unsigned)(unsigned short)f2h(O0[2 * rr + 1] * inv) << 16);
        unsigned u1 = (unsigned short)f2h(O1[2 * rr] * inv) | ((unsigned)(unsigned short)f2h(O1[2 * rr + 1] * inv) << 16);
        *(unsigned*)(ob + dvb) = u0;
        *(unsigned*)(ob + 32 + dvb) = u1;
    }
}

// ---------------- launch ----------------

extern "C" void kernel_launch(void* const* d_in, const int* in_sizes, int n_in,
                              void* d_out, int out_size, void* d_ws, size_t ws_size,
                              hipStream_t stream) {
    const float* x     = (const float*)d_in[0];
    const float* Woff1 = (const float*)d_in[1];
    const float* boff1 = (const float*)d_in[2];
    const float* Woff2 = (const float*)d_in[3];
    const float* boff2 = (const float*)d_in[4];
    const float* Wq    = (const float*)d_in[5];
    const float* bq    = (const float*)d_in[6];
    const float* Wk    = (const float*)d_in[7];
    const float* bk    = (const float*)d_in[8];
    const float* Wv    = (const float*)d_in[9];
    const float* bv    = (const float*)d_in[10];
    const float* Wo    = (const float*)d_in[11];
    const float* bo    = (const float*)d_in[12];

    char* ws = (char*)d_ws;
    // region0: hsplit+B2T (dead after gemm2) -- cat aliases it
    short* hsplit = (short*)(ws + 0);             // 2048*768*2  = 3,145,728
    short* B2T    = (short*)(ws + 3145728);       // 4096*768*2  = 6,291,456 (end 9,437,184)
    short* cat    = (short*)(ws + 0);             // 2048*2048*2 = 8,388,608 (alias)
    short* Wtqkv  = (short*)(ws + 9437184);       // 768*256*2   =   393,216
    short* WtoT   = (short*)(ws + 9830400);       // 256*2048*2  = 1,048,576
    short* xs     = (short*)(ws + 10878976);      // 16384*256*2 = 8,388,608
    short* qbuf   = (short*)(ws + 19267584);      // 8,388,608
    short* kbuf   = (short*)(ws + 27656192);      // 8,388,608
    short* vT     = (short*)(ws + 36044800);      // 8,388,608  (end 44,433,408)

    // prep
    split_w2_k<<<4096, 256, 0, stream>>>(Woff2, B2T);
    qkv_prep_k<<<768, 256, 0, stream>>>(Wq, Wk, Wv, Wtqkv);
    wo_prep_k<<<2048, 256, 0, stream>>>(Wo, WtoT);

    // offset network stage 1: exact fp32 + gelu + fp16 split
    gemm1_k<<<128, 256, 0, stream>>>(x, Woff1, boff1, hsplit);

    // stage 2 (f16 3-term, ~22-bit accurate) + fused tanh + bilinear resampling
    gemm_bt<1><<<(2048 / 64) * (4096 / 64), 256, 0, stream>>>(
        hsplit, B2T, boff2, nullptr, nullptr, xs, nullptr, nullptr, 2048, 4096, 768, x);

    // qkv projections (V written transposed per (bh,h); q pre-scaled by 0.125)
    gemm_bt<2><<<(16384 / 64) * (768 / 64), 256, 0, stream>>>(
        xs, Wtqkv, bq, bk, bv, qbuf, kbuf, vT, 16384, 768, 256, nullptr);

    // attention (swapped-operand, barrier-free)
    attn_k<<<512, 256, 0, stream>>>(qbuf, kbuf, vT, cat);

    // output projection (fp32 out)
    gemm_bt<3><<<(2048 / 64) * (256 / 64), 256, 0, stream>>>(
        cat, WtoT, bo, nullptr, nullptr, d_out, nullptr, nullptr, 2048, 256, 2048, nullptr);
}

// Round 5
// 221.706 us; speedup vs baseline: 1.3002x; 1.0223x over previous
//
#include <hip/hip_runtime.h>
#include <hip/hip_bf16.h>

typedef __attribute__((ext_vector_type(8))) _Float16 half8;   // 8 f16 = 4 VGPRs
typedef __attribute__((ext_vector_type(4))) float f32x4;
typedef __attribute__((ext_vector_type(16))) float f32x16;
typedef __attribute__((ext_vector_type(2))) unsigned uint2v;
typedef __attribute__((ext_vector_type(4))) unsigned uint4v;

#define MFMAH(a, b, c) __builtin_amdgcn_mfma_f32_16x16x32_f16((a), (b), (c), 0, 0, 0)
#define MFMA32(a, b, c) __builtin_amdgcn_mfma_f32_32x32x16_f16((a), (b), (c), 0, 0, 0)

__device__ __forceinline__ short f2h(float v) { _Float16 h = (_Float16)v; return __builtin_bit_cast(short, h); }
__device__ __forceinline__ f32x4 fzero() { f32x4 z = {0.f, 0.f, 0.f, 0.f}; return z; }

__device__ __forceinline__ void gl16(const void* g, void* l) {
    // async global->LDS, 16B per lane; LDS dest = base + lane*16 (wave-uniform base)
    __builtin_amdgcn_global_load_lds((const __attribute__((address_space(1))) unsigned*)g,
                                     (__attribute__((address_space(3))) unsigned*)l, 16, 0, 0);
}

__device__ __forceinline__ float gelu_tanh(float v) {
    float u = 0.7978845608028654f * (v + 0.044715f * v * v * v);
    return 0.5f * v * (1.f + tanhf(u));
}

// ---------------- prep kernels (fp32 -> fp16 containers as short) ----------------

__global__ void split_w2_k(const float* __restrict__ w, short* __restrict__ dst) {
    int i = blockIdx.x * 256 + threadIdx.x;        // 4096*256
    int n = i >> 8, k = i & 255;
    float v = w[(long)k * 4096 + n];
    _Float16 w1 = (_Float16)v;
    _Float16 w2 = (_Float16)(v - (float)w1);
    dst[n * 768 + k]       = __builtin_bit_cast(short, w1);
    dst[n * 768 + 256 + k] = __builtin_bit_cast(short, w1);
    dst[n * 768 + 512 + k] = __builtin_bit_cast(short, w2);
}

__global__ void qkv_prep_k(const float* __restrict__ Wq, const float* __restrict__ Wk,
                           const float* __restrict__ Wv, short* __restrict__ dst) {
    int i = blockIdx.x * 256 + threadIdx.x;        // 768*256
    int n = i >> 8, k = i & 255;
    const float* s = (n < 256) ? Wq : (n < 512) ? Wk : Wv;
    dst[i] = f2h(s[k * 256 + (n & 255)]);
}

__global__ void wo_prep_k(const float* __restrict__ Wo, short* __restrict__ dst) {
    int i = blockIdx.x * 256 + threadIdx.x;        // 256*2048
    int n = i >> 11, k = i & 2047;
    dst[i] = f2h(Wo[k * 256 + n]);
}

// ---------------- GEMM1: exact fp32, fused gelu + fp16 hi/lo split ----------------

__global__ __launch_bounds__(256) void gemm1_k(const float* __restrict__ x, const float* __restrict__ W,
                                               const float* __restrict__ bias, short* __restrict__ hs) {
    __shared__ float As[64][17];
    __shared__ float Bs[16][68];
    const int tid = threadIdx.x;
    const int bm = blockIdx.x >> 2, bn = blockIdx.x & 3;     // 32 x 4
    const int m0 = bm * 64, n0 = bn * 64;
    const int ty = tid >> 4, tx = tid & 15;
    float acc[4][4] = {};
    const int ar = tid >> 2, ak = (tid & 3) << 2;
    const int bk = tid >> 4, bc = (tid & 15) << 2;

    for (int k0 = 0; k0 < 256; k0 += 16) {
        __syncthreads();
        float4 av = *(const float4*)(x + (m0 + ar) * 256 + k0 + ak);
        As[ar][ak + 0] = av.x; As[ar][ak + 1] = av.y; As[ar][ak + 2] = av.z; As[ar][ak + 3] = av.w;
        *(float4*)&Bs[bk][bc] = *(const float4*)(W + (k0 + bk) * 256 + n0 + bc);
        __syncthreads();
#pragma unroll
        for (int kk = 0; kk < 16; ++kk) {
            float a_[4], b_[4];
#pragma unroll
            for (int i = 0; i < 4; ++i) a_[i] = As[ty * 4 + i][kk];
            *(float4*)b_ = *(const float4*)&Bs[kk][tx * 4];
#pragma unroll
            for (int i = 0; i < 4; ++i)
#pragma unroll
                for (int j = 0; j < 4; ++j) acc[i][j] += a_[i] * b_[j];
        }
    }
#pragma unroll
    for (int i = 0; i < 4; ++i) {
        int row = m0 + ty * 4 + i;
#pragma unroll
        for (int j = 0; j < 4; ++j) {
            int col = n0 + tx * 4 + j;
            float v = gelu_tanh(acc[i][j] + bias[col]);
            _Float16 h1 = (_Float16)v;
            _Float16 h2 = (_Float16)(v - (float)h1);
            hs[row * 768 + col]       = __builtin_bit_cast(short, h1);
            hs[row * 768 + 256 + col] = __builtin_bit_cast(short, h2);
            hs[row * 768 + 512 + col] = __builtin_bit_cast(short, h1);
        }
    }
}

// ---------------- m97-style 128x128 MFMA GEMM, global_load_lds staging ----------------
// 4 waves (2x2), BK=32, acc 4x4 per wave. C = A(M,K) * BT(N,K)^T.
// EPI 1: +bias, tanh -> fused bilinear grid-sample (balanced even/odd lanes)
// EPI 2: qkv scatter (out0=q*0.125, out1=k, out2=vT)

template <int EPI>
__global__ __launch_bounds__(256, 2) void gemm128(
    const short* __restrict__ A, const short* __restrict__ BT,
    const float* __restrict__ b0, const float* __restrict__ b1, const float* __restrict__ b2,
    void* __restrict__ out0, void* __restrict__ out1, void* __restrict__ out2,
    int M, int N, int K, const float* __restrict__ xsrc)
{
    __shared__ short As[128 * 32];
    __shared__ short Bs[128 * 32];

    const int tid = threadIdx.x;
    const int lane = tid & 63, w = tid >> 6;
    const int rl = lane & 15, g = lane >> 4;
    const int wr = w >> 1, wc = w & 1;
    const int nb = N >> 7;
    const int bm = blockIdx.x / nb, bn = blockIdx.x % nb;
    const int m0 = bm << 7, n0 = bn << 7;

    f32x4 acc[4][4];
#pragma unroll
    for (int m = 0; m < 4; ++m)
#pragma unroll
        for (int n = 0; n < 4; ++n) acc[m][n] = fzero();

    // staging: wave w owns rows [w*32, w*32+32) of both tiles; 2 issues of 16 rows each
    const short* ap = A + (long)(m0 + w * 32 + (lane >> 2)) * K + ((lane & 3) << 3);
    const short* bp = BT + (long)(n0 + w * 32 + (lane >> 2)) * K + ((lane & 3) << 3);
    short* lA0 = &As[(w * 32) * 32];
    short* lA1 = &As[(w * 32 + 16) * 32];
    short* lB0 = &Bs[(w * 32) * 32];
    short* lB1 = &Bs[(w * 32 + 16) * 32];
    const int krow = 16 * K;

    for (int k0 = 0; k0 < K; k0 += 32) {
        __syncthreads();                       // prev iter's ds_reads done
        gl16(ap + k0, lA0);
        gl16(ap + k0 + krow, lA1);
        gl16(bp + k0, lB0);
        gl16(bp + k0 + krow, lB1);
        __syncthreads();                       // staging drained (vmcnt 0 before barrier)
        half8 af[4], bf[4];
#pragma unroll
        for (int m = 0; m < 4; ++m) af[m] = *(const half8*)&As[(wr * 64 + m * 16 + rl) * 32 + g * 8];
#pragma unroll
        for (int n = 0; n < 4; ++n) bf[n] = *(const half8*)&Bs[(wc * 64 + n * 16 + rl) * 32 + g * 8];
#pragma unroll
        for (int m = 0; m < 4; ++m)
#pragma unroll
            for (int n = 0; n < 4; ++n) acc[m][n] = MFMAH(af[m], bf[n], acc[m][n]);
    }

#pragma unroll
    for (int m = 0; m < 4; ++m)
#pragma unroll
        for (int nt = 0; nt < 4; ++nt) {
            const int col = n0 + wc * 64 + nt * 16 + rl;
            if (EPI == 1) {
                float o4[4], po4[4];
                const float bb = b0[col];
#pragma unroll
                for (int j = 0; j < 4; ++j) o4[j] = tanhf(acc[m][nt][j] + bb);
#pragma unroll
                for (int j = 0; j < 4; ++j) po4[j] = __shfl_xor(o4[j], 1);
                const int jlo = (rl & 1) ? 2 : 0;      // even lanes: j 0,1; odd: j 2,3
                const int c = (col >> 1) & 255, d = col >> 9;
#pragma unroll
                for (int u = 0; u < 2; ++u) {
                    const int j = jlo + u;
                    float gx = (rl & 1) ? po4[j] : o4[j];
                    float gy = (rl & 1) ? o4[j] : po4[j];
                    gx = (gx + 1.f) * 127.5f;          // [0,255]
                    gy = (gy + 1.f) * 4095.5f;         // [0,8191]
                    float x0f = floorf(gx), y0f = floorf(gy);
                    float wx = gx - x0f, wy = gy - y0f;
                    int ix0 = (int)x0f, iy0 = (int)y0f;
                    int ix1 = min(ix0 + 1, 255), iy1 = min(iy0 + 1, 8191);
                    ix0 = max(min(ix0, 255), 0);
                    iy0 = max(min(iy0, 8191), 0);
                    ix1 = max(ix1, 0);
                    iy1 = max(iy1, 0);
                    const int row = m0 + wr * 64 + m * 16 + g * 4 + j;
                    const int b = row >> 10, t = row & 1023;
                    const float* xb = xsrc + b * 262144;
                    int r0 = (iy0 & 1023) << 8, r1 = (iy1 & 1023) << 8;
                    float v00 = xb[r0 + ix0], v01 = xb[r0 + ix1];
                    float v10 = xb[r1 + ix0], v11 = xb[r1 + ix1];
                    float r = v00 * (1.f - wy) * (1.f - wx) + v01 * (1.f - wy) * wx
                            + v10 * wy * (1.f - wx) + v11 * wy * wx;
                    ((short*)out0)[((b * 8 + d) * 1024 + t) * 256 + c] = f2h(r);
                }
            } else {   // EPI == 2
#pragma unroll
                for (int j = 0; j < 4; ++j) {
                    const long grow = m0 + wr * 64 + m * 16 + g * 4 + j;
                    if (col < 256) {
                        ((short*)out0)[grow * 256 + col] = f2h((acc[m][nt][j] + b0[col]) * 0.125f);
                    } else if (col < 512) {
                        ((short*)out1)[grow * 256 + (col - 256)] = f2h(acc[m][nt][j] + b1[col - 256]);
                    } else {
                        int np = col - 512, hh = np >> 6, dd = np & 63;
                        long bh = grow >> 10, t = grow & 1023;
                        ((short*)out2)[((bh * 4 + hh) * 64 + dd) * 1024 + t] = f2h(acc[m][nt][j] + b2[np]);
                    }
                }
            }
        }
}

// ---------------- 64x64 GEMM (kept for the small output projection) ----------------

__global__ __launch_bounds__(256, 2) void gemm_out(
    const short* __restrict__ A, const short* __restrict__ BT,
    const float* __restrict__ b0, float* __restrict__ out0, int M, int N, int K)
{
    __shared__ short As[64][40];
    __shared__ short Bs[64][40];

    const int tid = threadIdx.x;
    const int lane = tid & 63, wv = tid >> 6;
    const int rl = lane & 15, g = lane >> 4;
    const int nb = N >> 6;
    const int bm = blockIdx.x / nb, bn = blockIdx.x % nb;
    const long m0 = (long)bm * 64, n0 = (long)bn * 64;

    f32x4 acc[4];
#pragma unroll
    for (int nt = 0; nt < 4; ++nt) acc[nt] = fzero();

    const int srow = tid >> 2, scol = (tid & 3) << 3;
    const short* ap = A + (m0 + srow) * K + scol;
    const short* bp = BT + (n0 + srow) * K + scol;

    for (int k0 = 0; k0 < K; k0 += 32) {
        __syncthreads();
        *(half8*)&As[srow][scol] = *(const half8*)(ap + k0);
        *(half8*)&Bs[srow][scol] = *(const half8*)(bp + k0);
        __syncthreads();
        half8 af = *(const half8*)&As[wv * 16 + rl][g * 8];
#pragma unroll
        for (int nt = 0; nt < 4; ++nt) {
            half8 bfv = *(const half8*)&Bs[nt * 16 + rl][g * 8];
            acc[nt] = MFMAH(af, bfv, acc[nt]);
        }
    }

#pragma unroll
    for (int nt = 0; nt < 4; ++nt) {
        long gcol = n0 + nt * 16 + rl;
#pragma unroll
        for (int j = 0; j < 4; ++j) {
            long grow = m0 + wv * 16 + g * 4 + j;
            out0[grow * 256 + gcol] = acc[nt][j] + b0[gcol];
        }
    }
}

// ---------------- flash attention: swapped-operand, 32 q-rows/wave, no LDS ----------------

__global__ __launch_bounds__(256) void attn_k(const short* __restrict__ q, const short* __restrict__ km,
                                              const short* __restrict__ vT, short* __restrict__ oc) {
    const int lane = threadIdx.x & 63, wv = threadIdx.x >> 6;
    const int l31 = lane & 31, hi = lane >> 5;
    const int bhh = blockIdx.x >> 3;          // bh*4 + h  (64 combos)
    const int bh = bhh >> 2, h = bhh & 3;
    const int q0 = (blockIdx.x & 7) * 128 + wv * 32;

    const short* qb = q + (long)bh * 262144 + h * 64;
    const short* kb = km + (long)bh * 262144 + h * 64;
    const short* vb = vT + (long)bhh * 65536;

    half8 qf[4];
#pragma unroll
    for (int c = 0; c < 4; ++c)
        qf[c] = *(const half8*)(qb + (long)(q0 + l31) * 256 + c * 16 + hi * 8);

    float m_ = -1e30f, l_ = 0.f;
    f32x16 O0, O1;
#pragma unroll
    for (int r = 0; r < 16; ++r) { O0[r] = 0.f; O1[r] = 0.f; }

    for (int kk = 0; kk < 32; ++kk) {
        const int kbase = kk * 32;
        f32x16 S;
#pragma unroll
        for (int r = 0; r < 16; ++r) S[r] = 0.f;
#pragma unroll
        for (int c = 0; c < 4; ++c) {
            half8 kf = *(const half8*)(kb + (long)(kbase + l31) * 256 + c * 16 + hi * 8);
            S = MFMA32(kf, qf[c], S);
        }
        float mx = S[0];
#pragma unroll
        for (int r = 1; r < 16; ++r) mx = fmaxf(mx, S[r]);
        mx = fmaxf(mx, __shfl_xor(mx, 32));
        if (__any(mx > m_)) {                 // defer-max
            float mn = fmaxf(m_, mx);
            float sc = __expf(m_ - mn);
            m_ = mn;
            l_ *= sc;
#pragma unroll
            for (int r = 0; r < 16; ++r) { O0[r] *= sc; O1[r] *= sc; }
        }
        float p[16];
        float rs = 0.f;
#pragma unroll
        for (int r = 0; r < 16; ++r) { p[r] = __expf(S[r] - m_); rs += p[r]; }
        rs += __shfl_xor(rs, 32);
        l_ += rs;
        half8 PA[2];
#pragma unroll
        for (int c = 0; c < 2; ++c) {
            const int o = c * 8;
            unsigned a0 = __builtin_bit_cast(unsigned, __builtin_amdgcn_cvt_pkrtz(p[o + 0], p[o + 1]));
            unsigned b0v = __builtin_bit_cast(unsigned, __builtin_amdgcn_cvt_pkrtz(p[o + 4], p[o + 5]));
            unsigned a1 = __builtin_bit_cast(unsigned, __builtin_amdgcn_cvt_pkrtz(p[o + 2], p[o + 3]));
            unsigned b1v = __builtin_bit_cast(unsigned, __builtin_amdgcn_cvt_pkrtz(p[o + 6], p[o + 7]));
            uint2v r0 = __builtin_amdgcn_permlane32_swap(a0, b0v, false, false);
            uint2v r1 = __builtin_amdgcn_permlane32_swap(a1, b1v, false, false);
            uint4v wpk = {r0[0], r1[0], r0[1], r1[1]};
            PA[c] = __builtin_bit_cast(half8, wpk);
        }
#pragma unroll
        for (int c = 0; c < 2; ++c) {
            half8 v0 = *(const half8*)(vb + (long)l31 * 1024 + kbase + c * 16 + hi * 8);
            half8 v1 = *(const half8*)(vb + (long)(32 + l31) * 1024 + kbase + c * 16 + hi * 8);
            O0 = MFMA32(v0, PA[c], O0);
            O1 = MFMA32(v1, PA[c], O1);
        }
    }

    const float inv = 1.f / l_;
    const int b = bh >> 3, d = bh & 7;
    const int t = q0 + l31;
    short* ob = oc + ((long)(b * 1024 + t) * 8 + d) * 256 + h * 64;
#pragma unroll
    for (int rr = 0; rr < 8; ++rr) {
        int dvb = (rr & 1) * 2 + 8 * (rr >> 1) + 4 * hi;
        unsigned u0 = (unsigned short)f2h(O0[2 * rr] * inv) | ((unsigned)(unsigned short)f2h(O0[2 * rr + 1] * inv) << 16);
        unsigned u1 = (unsigned short)f2h(O1[2 * rr] * inv) | ((unsigned)(unsigned short)f2h(O1[2 * rr + 1] * inv) << 16);
        *(unsigned*)(ob + dvb) = u0;
        *(unsigned*)(ob + 32 + dvb) = u1;
    }
}

// ---------------- launch ----------------

extern "C" void kernel_launch(void* const* d_in, const int* in_sizes, int n_in,
                              void* d_out, int out_size, void* d_ws, size_t ws_size,
                              hipStream_t stream) {
    const float* x     = (const float*)d_in[0];
    const float* Woff1 = (const float*)d_in[1];
    const float* boff1 = (const float*)d_in[2];
    const float* Woff2 = (const float*)d_in[3];
    const float* boff2 = (const float*)d_in[4];
    const float* Wq    = (const float*)d_in[5];
    const float* bq    = (const float*)d_in[6];
    const float* Wk    = (const float*)d_in[7];
    const float* bk    = (const float*)d_in[8];
    const float* Wv    = (const float*)d_in[9];
    const float* bv    = (const float*)d_in[10];
    const float* Wo    = (const float*)d_in[11];
    const float* bo    = (const float*)d_in[12];

    char* ws = (char*)d_ws;
    short* hsplit = (short*)(ws + 0);             // 2048*768*2  = 3,145,728
    short* B2T    = (short*)(ws + 3145728);       // 4096*768*2  = 6,291,456 (end 9,437,184)
    short* cat    = (short*)(ws + 0);             // 2048*2048*2 = 8,388,608 (alias, after B2T dead)
    short* Wtqkv  = (short*)(ws + 9437184);       // 768*256*2   =   393,216
    short* WtoT   = (short*)(ws + 9830400);       // 256*2048*2  = 1,048,576
    short* xs     = (short*)(ws + 10878976);      // 16384*256*2 = 8,388,608
    short* qbuf   = (short*)(ws + 19267584);      // 8,388,608
    short* kbuf   = (short*)(ws + 27656192);      // 8,388,608
    short* vT     = (short*)(ws + 36044800);      // 8,388,608  (end 44,433,408)

    // prep
    split_w2_k<<<4096, 256, 0, stream>>>(Woff2, B2T);
    qkv_prep_k<<<768, 256, 0, stream>>>(Wq, Wk, Wv, Wtqkv);
    wo_prep_k<<<2048, 256, 0, stream>>>(Wo, WtoT);

    // offset network stage 1: exact fp32 + gelu + fp16 split
    gemm1_k<<<128, 256, 0, stream>>>(x, Woff1, boff1, hsplit);

    // stage 2 (f16 3-term) + fused tanh + bilinear resampling
    gemm128<1><<<(2048 / 128) * (4096 / 128), 256, 0, stream>>>(
        hsplit, B2T, boff2, nullptr, nullptr, xs, nullptr, nullptr, 2048, 4096, 768, x);

    // qkv projections (V transposed per (bh,h); q pre-scaled by 0.125)
    gemm128<2><<<(16384 / 128) * (768 / 128), 256, 0, stream>>>(
        xs, Wtqkv, bq, bk, bv, qbuf, kbuf, vT, 16384, 768, 256, nullptr);

    // attention (swapped-operand, barrier-free)
    attn_k<<<512, 256, 0, stream>>>(qbuf, kbuf, vT, cat);

    // output projection (fp32 out)
    gemm_out<<<(2048 / 64) * (256 / 64), 256, 0, stream>>>(
        cat, WtoT, bo, (float*)d_out, 2048, 256, 2048);
}

// Round 6
// 203.323 us; speedup vs baseline: 1.4177x; 1.0904x over previous
//
#include <hip/hip_runtime.h>
#include <hip/hip_bf16.h>

typedef __attribute__((ext_vector_type(8))) _Float16 half8;   // 8 f16 = 4 VGPRs
typedef __attribute__((ext_vector_type(4))) float f32x4;
typedef __attribute__((ext_vector_type(16))) float f32x16;
typedef __attribute__((ext_vector_type(2))) unsigned uint2v;
typedef __attribute__((ext_vector_type(4))) unsigned uint4v;

#define MFMAH(a, b, c) __builtin_amdgcn_mfma_f32_16x16x32_f16((a), (b), (c), 0, 0, 0)
#define MFMA32(a, b, c) __builtin_amdgcn_mfma_f32_32x32x16_f16((a), (b), (c), 0, 0, 0)

__device__ __forceinline__ short f2h(float v) { _Float16 h = (_Float16)v; return __builtin_bit_cast(short, h); }
__device__ __forceinline__ f32x4 fzero() { f32x4 z = {0.f, 0.f, 0.f, 0.f}; return z; }

__device__ __forceinline__ void gl16(const void* g, void* l) {
    // async global->LDS, 16B/lane; LDS dest = wave-uniform base + lane*16
    __builtin_amdgcn_global_load_lds((const __attribute__((address_space(1))) unsigned*)g,
                                     (__attribute__((address_space(3))) unsigned*)l, 16, 0, 0);
}

__device__ __forceinline__ float gelu_tanh(float v) {
    float u = 0.7978845608028654f * (v + 0.044715f * v * v * v);
    return 0.5f * v * (1.f + tanhf(u));
}

// ---------------- prep kernels ----------------

// W_off2 (256,4096) -> B2T (4096,768) f16 [w1|w1|w2], LDS-tiled transpose
__global__ __launch_bounds__(256) void split_w2_k(const float* __restrict__ w, short* __restrict__ dst) {
    __shared__ float t[64][65];
    const int tid = threadIdx.x;
    const int bk = blockIdx.x >> 6, bn = blockIdx.x & 63;    // 4 x 64 blocks
    const int k0 = bk * 64, n0 = bn * 64;
#pragma unroll
    for (int p = 0; p < 16; ++p) {
        int idx = p * 256 + tid, r = idx >> 6, c = idx & 63;
        t[r][c] = w[(long)(k0 + r) * 4096 + n0 + c];
    }
    __syncthreads();
#pragma unroll
    for (int p = 0; p < 16; ++p) {
        int idx = p * 256 + tid, nr = idx >> 6, kc = idx & 63;
        float v = t[kc][nr];
        _Float16 w1 = (_Float16)v;
        _Float16 w2 = (_Float16)(v - (float)w1);
        long base = (long)(n0 + nr) * 768 + k0 + kc;
        dst[base]       = __builtin_bit_cast(short, w1);
        dst[base + 256] = __builtin_bit_cast(short, w1);
        dst[base + 512] = __builtin_bit_cast(short, w2);
    }
}

__global__ void qkv_prep_k(const float* __restrict__ Wq, const float* __restrict__ Wk,
                           const float* __restrict__ Wv, short* __restrict__ dst) {
    int i = blockIdx.x * 256 + threadIdx.x;        // 768*256
    int n = i >> 8, k = i & 255;
    const float* s = (n < 256) ? Wq : (n < 512) ? Wk : Wv;
    dst[i] = f2h(s[k * 256 + (n & 255)]);
}

__global__ void wo_prep_k(const float* __restrict__ Wo, short* __restrict__ dst) {
    int i = blockIdx.x * 256 + threadIdx.x;        // 256*2048
    int n = i >> 11, k = i & 2047;
    dst[i] = f2h(Wo[k * 256 + n]);
}

// ---------------- GEMM1: exact fp32, fused gelu + fp16 hi/lo split ----------------

__global__ __launch_bounds__(256) void gemm1_k(const float* __restrict__ x, const float* __restrict__ W,
                                               const float* __restrict__ bias, short* __restrict__ hs) {
    __shared__ float As[64][17];
    __shared__ float Bs[16][68];
    const int tid = threadIdx.x;
    const int bm = blockIdx.x >> 2, bn = blockIdx.x & 3;     // 32 x 4
    const int m0 = bm * 64, n0 = bn * 64;
    const int ty = tid >> 4, tx = tid & 15;
    float acc[4][4] = {};
    const int ar = tid >> 2, ak = (tid & 3) << 2;
    const int bk = tid >> 4, bc = (tid & 15) << 2;

    for (int k0 = 0; k0 < 256; k0 += 16) {
        __syncthreads();
        float4 av = *(const float4*)(x + (m0 + ar) * 256 + k0 + ak);
        As[ar][ak + 0] = av.x; As[ar][ak + 1] = av.y; As[ar][ak + 2] = av.z; As[ar][ak + 3] = av.w;
        *(float4*)&Bs[bk][bc] = *(const float4*)(W + (k0 + bk) * 256 + n0 + bc);
        __syncthreads();
#pragma unroll
        for (int kk = 0; kk < 16; ++kk) {
            float a_[4], b_[4];
#pragma unroll
            for (int i = 0; i < 4; ++i) a_[i] = As[ty * 4 + i][kk];
            *(float4*)b_ = *(const float4*)&Bs[kk][tx * 4];
#pragma unroll
            for (int i = 0; i < 4; ++i)
#pragma unroll
                for (int j = 0; j < 4; ++j) acc[i][j] += a_[i] * b_[j];
        }
    }
#pragma unroll
    for (int i = 0; i < 4; ++i) {
        int row = m0 + ty * 4 + i;
#pragma unroll
        for (int j = 0; j < 4; ++j) {
            int col = n0 + tx * 4 + j;
            float v = gelu_tanh(acc[i][j] + bias[col]);
            _Float16 h1 = (_Float16)v;
            _Float16 h2 = (_Float16)(v - (float)h1);
            hs[row * 768 + col]       = __builtin_bit_cast(short, h1);
            hs[row * 768 + 256 + col] = __builtin_bit_cast(short, h2);
            hs[row * 768 + 512 + col] = __builtin_bit_cast(short, h1);
        }
    }
}

// ---------------- 128x128 MFMA GEMM, double-buffered global_load_lds ----------------
// 4 waves (2x2), BK=32, acc 4x4/wave. C = A(M,K)*BT(N,K)^T. T3-min schedule:
// STAGE(next) -> ds_read+MFMA(cur) -> barrier (compiler emits vmcnt0+lgkmcnt0).
// EPI 1: +bias, tanh -> fused bilinear grid-sample, LDS-staged contiguous stores
// EPI 2: qkv scatter (out0=q*0.125, out1=k, out2=vT)
// EPI 3: fp32 split-K partial (blockIdx.y = ks; A,BT k-offset ks*256)

template <int EPI>
__global__ __launch_bounds__(256, 2) void gemm128(
    const short* __restrict__ A, const short* __restrict__ BT,
    const float* __restrict__ b0, const float* __restrict__ b1, const float* __restrict__ b2,
    void* __restrict__ out0, void* __restrict__ out1, void* __restrict__ out2,
    int M, int N, int K, int lda, int ldb, const float* __restrict__ xsrc)
{
    __shared__ short lds[16384];          // 32 KB: 4 x 4096 (A0,A1,B0,B1)
    short* As0 = lds;
    short* As1 = lds + 4096;
    short* Bs0 = lds + 8192;
    short* Bs1 = lds + 12288;

    const int tid = threadIdx.x;
    const int lane = tid & 63, w = tid >> 6;
    const int rl = lane & 15, g = lane >> 4;
    const int wr = w >> 1, wc = w & 1;
    const int nb = N >> 7;
    const int bm = blockIdx.x / nb, bn = blockIdx.x % nb;
    const int m0 = bm << 7, n0 = bn << 7;

    if (EPI == 3) { A += blockIdx.y << 8; BT += blockIdx.y << 8; }

    f32x4 acc[4][4];
#pragma unroll
    for (int m = 0; m < 4; ++m)
#pragma unroll
        for (int n = 0; n < 4; ++n) acc[m][n] = fzero();

    const short* ap = A + (long)(m0 + w * 32 + (lane >> 2)) * lda + ((lane & 3) << 3);
    const short* bp = BT + (long)(n0 + w * 32 + (lane >> 2)) * ldb + ((lane & 3) << 3);
    const int woff = w * 1024;

#define STAGE(dA, dB, kk) do { \
        gl16(ap + (kk), (dA) + woff); \
        gl16(ap + (kk) + 16 * lda, (dA) + woff + 512); \
        gl16(bp + (kk), (dB) + woff); \
        gl16(bp + (kk) + 16 * ldb, (dB) + woff + 512); } while (0)

    const int nt_ = K >> 5;
    STAGE(As0, Bs0, 0);
    __syncthreads();
    for (int t = 0; t < nt_; ++t) {
        const short* cA = (t & 1) ? As1 : As0;
        const short* cB = (t & 1) ? Bs1 : Bs0;
        short* nA = (t & 1) ? As0 : As1;
        short* nB = (t & 1) ? Bs0 : Bs1;
        if (t + 1 < nt_) STAGE(nA, nB, (t + 1) << 5);
        half8 af[4], bf[4];
#pragma unroll
        for (int m = 0; m < 4; ++m) af[m] = *(const half8*)&cA[(wr * 64 + m * 16 + rl) * 32 + g * 8];
#pragma unroll
        for (int n = 0; n < 4; ++n) bf[n] = *(const half8*)&cB[(wc * 64 + n * 16 + rl) * 32 + g * 8];
#pragma unroll
        for (int m = 0; m < 4; ++m)
#pragma unroll
            for (int n = 0; n < 4; ++n) acc[m][n] = MFMAH(af[m], bf[n], acc[m][n]);
        __syncthreads();
    }
#undef STAGE

    if (EPI == 1) {
        // sample into LDS tile [128][72] (stride 144B: 16B-aligned, bank-diagonal)
        const int d = n0 >> 9, c0 = (n0 >> 1) & 255;
#pragma unroll
        for (int m = 0; m < 4; ++m)
#pragma unroll
            for (int nt = 0; nt < 4; ++nt) {
                const int col = n0 + wc * 64 + nt * 16 + rl;
                float o4[4], po4[4];
                const float bb = b0[col];
#pragma unroll
                for (int j = 0; j < 4; ++j) o4[j] = tanhf(acc[m][nt][j] + bb);
#pragma unroll
                for (int j = 0; j < 4; ++j) po4[j] = __shfl_xor(o4[j], 1);
                const int jlo = (rl & 1) ? 2 : 0;
                const int cl = (wc * 64 + nt * 16 + rl) >> 1;
#pragma unroll
                for (int u = 0; u < 2; ++u) {
                    const int j = jlo + u;
                    float gx = (rl & 1) ? po4[j] : o4[j];
                    float gy = (rl & 1) ? o4[j] : po4[j];
                    gx = (gx + 1.f) * 127.5f;          // [0,255]
                    gy = (gy + 1.f) * 4095.5f;         // [0,8191]
                    float x0f = floorf(gx), y0f = floorf(gy);
                    float wx = gx - x0f, wy = gy - y0f;
                    int ix0 = (int)x0f, iy0 = (int)y0f;
                    int ix1 = min(ix0 + 1, 255), iy1 = min(iy0 + 1, 8191);
                    ix0 = max(min(ix0, 255), 0);
                    iy0 = max(min(iy0, 8191), 0);
                    ix1 = max(ix1, 0);
                    iy1 = max(iy1, 0);
                    const int rowl = wr * 64 + m * 16 + g * 4 + j;
                    const int b = (m0 + rowl) >> 10;
                    const float* xb = xsrc + b * 262144;
                    int r0 = (iy0 & 1023) << 8, r1 = (iy1 & 1023) << 8;
                    float v00 = xb[r0 + ix0], v01 = xb[r0 + ix1];
                    float v10 = xb[r1 + ix0], v11 = xb[r1 + ix1];
                    float r = v00 * (1.f - wy) * (1.f - wx) + v01 * (1.f - wy) * wx
                            + v10 * wy * (1.f - wx) + v11 * wy * wx;
                    lds[rowl * 72 + cl] = f2h(r);
                }
            }
        __syncthreads();
        // cooperative contiguous stores: 128 rows x 128B
        const int b = m0 >> 10, t0 = m0 & 1023;
        short* xo = (short*)out0 + ((long)(b * 8 + d) * 1024 + t0) * 256 + c0;
#pragma unroll
        for (int p = 0; p < 4; ++p) {
            int idx = p * 256 + tid, rowl = idx >> 3, ch = idx & 7;
            *(half8*)(xo + rowl * 256 + ch * 8) = *(const half8*)&lds[rowl * 72 + ch * 8];
        }
    } else if (EPI == 2) {
#pragma unroll
        for (int m = 0; m < 4; ++m)
#pragma unroll
            for (int nt = 0; nt < 4; ++nt) {
                const int col = n0 + wc * 64 + nt * 16 + rl;
#pragma unroll
                for (int j = 0; j < 4; ++j) {
                    const long grow = m0 + wr * 64 + m * 16 + g * 4 + j;
                    if (col < 256) {
                        ((short*)out0)[grow * 256 + col] = f2h((acc[m][nt][j] + b0[col]) * 0.125f);
                    } else if (col < 512) {
                        ((short*)out1)[grow * 256 + (col - 256)] = f2h(acc[m][nt][j] + b1[col - 256]);
                    } else {
                        int np = col - 512, hh = np >> 6, dd = np & 63;
                        long bh = grow >> 10, t = grow & 1023;
                        ((short*)out2)[((bh * 4 + hh) * 64 + dd) * 1024 + t] = f2h(acc[m][nt][j] + b2[np]);
                    }
                }
            }
    } else {  // EPI == 3: fp32 partial
        float* op = (float*)out0 + (long)blockIdx.y * M * N;
#pragma unroll
        for (int m = 0; m < 4; ++m)
#pragma unroll
            for (int nt = 0; nt < 4; ++nt) {
                const int col = n0 + wc * 64 + nt * 16 + rl;
#pragma unroll
                for (int j = 0; j < 4; ++j) {
                    const long grow = m0 + wr * 64 + m * 16 + g * 4 + j;
                    op[grow * N + col] = acc[m][nt][j];
                }
            }
    }
}

// sum split-K partials + bias -> fp32 out
__global__ void reduce_out_k(const float* __restrict__ p, const float* __restrict__ bo,
                             float* __restrict__ out) {
    int i = blockIdx.x * 256 + threadIdx.x;   // 524288
    float s = bo[i & 255];
#pragma unroll
    for (int ks = 0; ks < 8; ++ks) s += p[ks * 524288 + i];
    out[i] = s;
}

// ---------------- flash attention: swapped-operand, 32 q-rows/wave, no LDS ----------------

__global__ __launch_bounds__(256) void attn_k(const short* __restrict__ q, const short* __restrict__ km,
                                              const short* __restrict__ vT, short* __restrict__ oc) {
    const int lane = threadIdx.x & 63, wv = threadIdx.x >> 6;
    const int l31 = lane & 31, hi = lane >> 5;
    const int bhh = blockIdx.x >> 3;          // bh*4 + h
    const int bh = bhh >> 2, h = bhh & 3;
    const int q0 = (blockIdx.x & 7) * 128 + wv * 32;

    const short* qb = q + (long)bh * 262144 + h * 64;
    const short* kb = km + (long)bh * 262144 + h * 64;
    const short* vb = vT + (long)bhh * 65536;

    half8 qf[4];
#pragma unroll
    for (int c = 0; c < 4; ++c)
        qf[c] = *(const half8*)(qb + (long)(q0 + l31) * 256 + c * 16 + hi * 8);

    float m_ = -1e30f, l_ = 0.f;
    f32x16 O0, O1;
#pragma unroll
    for (int r = 0; r < 16; ++r) { O0[r] = 0.f; O1[r] = 0.f; }

    for (int kk = 0; kk < 32; ++kk) {
        const int kbase = kk * 32;
        f32x16 S;
#pragma unroll
        for (int r = 0; r < 16; ++r) S[r] = 0.f;
#pragma unroll
        for (int c = 0; c < 4; ++c) {
            half8 kf = *(const half8*)(kb + (long)(kbase + l31) * 256 + c * 16 + hi * 8);
            S = MFMA32(kf, qf[c], S);
        }
        float mx = S[0];
#pragma unroll
        for (int r = 1; r < 16; ++r) mx = fmaxf(mx, S[r]);
        mx = fmaxf(mx, __shfl_xor(mx, 32));
        if (__any(mx > m_)) {                 // defer-max
            float mn = fmaxf(m_, mx);
            float sc = __expf(m_ - mn);
            m_ = mn;
            l_ *= sc;
#pragma unroll
            for (int r = 0; r < 16; ++r) { O0[r] *= sc; O1[r] *= sc; }
        }
        float p[16];
        float rs = 0.f;
#pragma unroll
        for (int r = 0; r < 16; ++r) { p[r] = __expf(S[r] - m_); rs += p[r]; }
        rs += __shfl_xor(rs, 32);
        l_ += rs;
        half8 PA[2];
#pragma unroll
        for (int c = 0; c < 2; ++c) {
            const int o = c * 8;
            unsigned a0 = __builtin_bit_cast(unsigned, __builtin_amdgcn_cvt_pkrtz(p[o + 0], p[o + 1]));
            unsigned b0v = __builtin_bit_cast(unsigned, __builtin_amdgcn_cvt_pkrtz(p[o + 4], p[o + 5]));
            unsigned a1 = __builtin_bit_cast(unsigned, __builtin_amdgcn_cvt_pkrtz(p[o + 2], p[o + 3]));
            unsigned b1v = __builtin_bit_cast(unsigned, __builtin_amdgcn_cvt_pkrtz(p[o + 6], p[o + 7]));
            uint2v r0 = __builtin_amdgcn_permlane32_swap(a0, b0v, false, false);
            uint2v r1 = __builtin_amdgcn_permlane32_swap(a1, b1v, false, false);
            uint4v wpk = {r0[0], r1[0], r0[1], r1[1]};
            PA[c] = __builtin_bit_cast(half8, wpk);
        }
#pragma unroll
        for (int c = 0; c < 2; ++c) {
            half8 v0 = *(const half8*)(vb + (long)l31 * 1024 + kbase + c * 16 + hi * 8);
            half8 v1 = *(const half8*)(vb + (long)(32 + l31) * 1024 + kbase + c * 16 + hi * 8);
            O0 = MFMA32(v0, PA[c], O0);
            O1 = MFMA32(v1, PA[c], O1);
        }
    }

    const float inv = 1.f / l_;
    const int b = bh >> 3, d = bh & 7;
    const int t = q0 + l31;
    short* ob = oc + ((long)(b * 1024 + t) * 8 + d) * 256 + h * 64;
#pragma unroll
    for (int rr = 0; rr < 8; ++rr) {
        int dvb = (rr & 1) * 2 + 8 * (rr >> 1) + 4 * hi;
        unsigned u0 = (unsigned short)f2h(O0[2 * rr] * inv) | ((unsigned)(unsigned short)f2h(O0[2 * rr + 1] * inv) << 16);
        unsigned u1 = (unsigned short)f2h(O1[2 * rr] * inv) | ((unsigned)(unsigned short)f2h(O1[2 * rr + 1] * inv) << 16);
        *(unsigned*)(ob + dvb) = u0;
        *(unsigned*)(ob + 32 + dvb) = u1;
    }
}

// ---------------- launch ----------------

extern "C" void kernel_launch(void* const* d_in, const int* in_sizes, int n_in,
                              void* d_out, int out_size, void* d_ws, size_t ws_size,
                              hipStream_t stream) {
    const float* x     = (const float*)d_in[0];
    const float* Woff1 = (const float*)d_in[1];
    const float* boff1 = (const float*)d_in[2];
    const float* Woff2 = (const float*)d_in[3];
    const float* boff2 = (const float*)d_in[4];
    const float* Wq    = (const float*)d_in[5];
    const float* bq    = (const float*)d_in[6];
    const float* Wk    = (const float*)d_in[7];
    const float* bk    = (const float*)d_in[8];
    const float* Wv    = (const float*)d_in[9];
    const float* bv    = (const float*)d_in[10];
    const float* Wo    = (const float*)d_in[11];
    const float* bo    = (const float*)d_in[12];

    char* ws = (char*)d_ws;
    short* hsplit = (short*)(ws + 0);             // 2048*768*2  = 3,145,728
    short* B2T    = (short*)(ws + 3145728);       // 4096*768*2  = 6,291,456 (end 9,437,184)
    short* cat    = (short*)(ws + 0);             // 2048*2048*2 = 8,388,608 (alias; B2T/hsplit dead)
    short* Wtqkv  = (short*)(ws + 9437184);       // 768*256*2   =   393,216
    short* WtoT   = (short*)(ws + 9830400);       // 256*2048*2  = 1,048,576
    short* xs     = (short*)(ws + 10878976);      // 16384*256*2 = 8,388,608
    short* qbuf   = (short*)(ws + 19267584);      // 8,388,608
    short* kbuf   = (short*)(ws + 27656192);      // 8,388,608
    short* vT     = (short*)(ws + 36044800);      // 8,388,608  (end 44,433,408)
    float* parts  = (float*)(ws + 44433408);      // 8*2048*256*4 = 16,777,216 (end 61,210,624)

    // prep
    split_w2_k<<<256, 256, 0, stream>>>(Woff2, B2T);
    qkv_prep_k<<<768, 256, 0, stream>>>(Wq, Wk, Wv, Wtqkv);
    wo_prep_k<<<2048, 256, 0, stream>>>(Wo, WtoT);

    // offset network stage 1: exact fp32 + gelu + fp16 split
    gemm1_k<<<128, 256, 0, stream>>>(x, Woff1, boff1, hsplit);

    // stage 2 (f16 3-term) + fused tanh + bilinear resampling
    gemm128<1><<<(2048 / 128) * (4096 / 128), 256, 0, stream>>>(
        hsplit, B2T, boff2, nullptr, nullptr, xs, nullptr, nullptr, 2048, 4096, 768, 768, 768, x);

    // qkv projections (V transposed per (bh,h); q pre-scaled by 0.125)
    gemm128<2><<<(16384 / 128) * (768 / 128), 256, 0, stream>>>(
        xs, Wtqkv, bq, bk, bv, qbuf, kbuf, vT, 16384, 768, 256, 256, 256, nullptr);

    // attention (swapped-operand, barrier-free)
    attn_k<<<512, 256, 0, stream>>>(qbuf, kbuf, vT, cat);

    // output projection: split-K=8 partials + reduce
    gemm128<3><<<dim3((2048 / 128) * (256 / 128), 8), 256, 0, stream>>>(
        cat, WtoT, nullptr, nullptr, nullptr, parts, nullptr, nullptr, 2048, 256, 256, 2048, 2048, nullptr);
    reduce_out_k<<<2048, 256, 0, stream>>>(parts, bo, (float*)d_out);
}

// Round 7
// 202.393 us; speedup vs baseline: 1.4242x; 1.0046x over previous
//
#include <hip/hip_runtime.h>
#include <hip/hip_bf16.h>

typedef __attribute__((ext_vector_type(8))) _Float16 half8;   // 8 f16 = 4 VGPRs
typedef __attribute__((ext_vector_type(4))) float f32x4;
typedef __attribute__((ext_vector_type(16))) float f32x16;
typedef __attribute__((ext_vector_type(2))) unsigned uint2v;
typedef __attribute__((ext_vector_type(4))) unsigned uint4v;

#define MFMAH(a, b, c) __builtin_amdgcn_mfma_f32_16x16x32_f16((a), (b), (c), 0, 0, 0)
#define MFMA32(a, b, c) __builtin_amdgcn_mfma_f32_32x32x16_f16((a), (b), (c), 0, 0, 0)

__device__ __forceinline__ short f2h(float v) { _Float16 h = (_Float16)v; return __builtin_bit_cast(short, h); }
__device__ __forceinline__ f32x4 fzero() { f32x4 z = {0.f, 0.f, 0.f, 0.f}; return z; }

__device__ __forceinline__ void gl16(const void* g, void* l) {
    // async global->LDS, 16B/lane; LDS dest = wave-uniform base + lane*16
    __builtin_amdgcn_global_load_lds((const __attribute__((address_space(1))) unsigned*)g,
                                     (__attribute__((address_space(3))) unsigned*)l, 16, 0, 0);
}

__device__ __forceinline__ float gelu_tanh(float v) {
    float u = 0.7978845608028654f * (v + 0.044715f * v * v * v);
    return 0.5f * v * (1.f + tanhf(u));
}

// ---------------- prep kernels ----------------

// W_off2 (256,4096) -> B2T (4096,768) f16 [w1|w1|w2], LDS-tiled transpose
__global__ __launch_bounds__(256) void split_w2_k(const float* __restrict__ w, short* __restrict__ dst) {
    __shared__ float t[64][65];
    const int tid = threadIdx.x;
    const int bk = blockIdx.x >> 6, bn = blockIdx.x & 63;    // 4 x 64 blocks
    const int k0 = bk * 64, n0 = bn * 64;
#pragma unroll
    for (int p = 0; p < 16; ++p) {
        int idx = p * 256 + tid, r = idx >> 6, c = idx & 63;
        t[r][c] = w[(long)(k0 + r) * 4096 + n0 + c];
    }
    __syncthreads();
#pragma unroll
    for (int p = 0; p < 16; ++p) {
        int idx = p * 256 + tid, nr = idx >> 6, kc = idx & 63;
        float v = t[kc][nr];
        _Float16 w1 = (_Float16)v;
        _Float16 w2 = (_Float16)(v - (float)w1);
        long base = (long)(n0 + nr) * 768 + k0 + kc;
        dst[base]       = __builtin_bit_cast(short, w1);
        dst[base + 256] = __builtin_bit_cast(short, w1);
        dst[base + 512] = __builtin_bit_cast(short, w2);
    }
}

__global__ void qkv_prep_k(const float* __restrict__ Wq, const float* __restrict__ Wk,
                           const float* __restrict__ Wv, short* __restrict__ dst) {
    int i = blockIdx.x * 256 + threadIdx.x;        // 768*256
    int n = i >> 8, k = i & 255;
    const float* s = (n < 256) ? Wq : (n < 512) ? Wk : Wv;
    dst[i] = f2h(s[k * 256 + (n & 255)]);
}

__global__ void wo_prep_k(const float* __restrict__ Wo, short* __restrict__ dst) {
    int i = blockIdx.x * 256 + threadIdx.x;        // 256*2048
    int n = i >> 11, k = i & 2047;
    dst[i] = f2h(Wo[k * 256 + n]);
}

// ---------------- GEMM1: exact fp32, fused gelu + fp16 hi/lo split ----------------

__global__ __launch_bounds__(256) void gemm1_k(const float* __restrict__ x, const float* __restrict__ W,
                                               const float* __restrict__ bias, short* __restrict__ hs) {
    __shared__ float As[64][17];
    __shared__ float Bs[16][68];
    const int tid = threadIdx.x;
    const int bm = blockIdx.x >> 2, bn = blockIdx.x & 3;     // 32 x 4
    const int m0 = bm * 64, n0 = bn * 64;
    const int ty = tid >> 4, tx = tid & 15;
    float acc[4][4] = {};
    const int ar = tid >> 2, ak = (tid & 3) << 2;
    const int bk = tid >> 4, bc = (tid & 15) << 2;

    for (int k0 = 0; k0 < 256; k0 += 16) {
        __syncthreads();
        float4 av = *(const float4*)(x + (m0 + ar) * 256 + k0 + ak);
        As[ar][ak + 0] = av.x; As[ar][ak + 1] = av.y; As[ar][ak + 2] = av.z; As[ar][ak + 3] = av.w;
        *(float4*)&Bs[bk][bc] = *(const float4*)(W + (k0 + bk) * 256 + n0 + bc);
        __syncthreads();
#pragma unroll
        for (int kk = 0; kk < 16; ++kk) {
            float a_[4], b_[4];
#pragma unroll
            for (int i = 0; i < 4; ++i) a_[i] = As[ty * 4 + i][kk];
            *(float4*)b_ = *(const float4*)&Bs[kk][tx * 4];
#pragma unroll
            for (int i = 0; i < 4; ++i)
#pragma unroll
                for (int j = 0; j < 4; ++j) acc[i][j] += a_[i] * b_[j];
        }
    }
#pragma unroll
    for (int i = 0; i < 4; ++i) {
        int row = m0 + ty * 4 + i;
#pragma unroll
        for (int j = 0; j < 4; ++j) {
            int col = n0 + tx * 4 + j;
            float v = gelu_tanh(acc[i][j] + bias[col]);
            _Float16 h1 = (_Float16)v;
            _Float16 h2 = (_Float16)(v - (float)h1);
            hs[row * 768 + col]       = __builtin_bit_cast(short, h1);
            hs[row * 768 + 256 + col] = __builtin_bit_cast(short, h2);
            hs[row * 768 + 512 + col] = __builtin_bit_cast(short, h1);
        }
    }
}

// ---------------- 128x128 MFMA GEMM, double-buffered global_load_lds ----------------
// 4 waves (2x2), BK=32, acc 4x4/wave. C = A(M,K)*BT(N,K)^T.
// EPI 1: +bias, tanh -> fused bilinear grid-sample, LDS-staged contiguous stores
// EPI 2: qkv scatter (out0=q*0.125, out1=k, out2=vT)
// EPI 3: fp32 split-K partial (blockIdx.y = ks; A,BT k-offset ks*256)

template <int EPI>
__global__ __launch_bounds__(256, 2) void gemm128(
    const short* __restrict__ A, const short* __restrict__ BT,
    const float* __restrict__ b0, const float* __restrict__ b1, const float* __restrict__ b2,
    void* __restrict__ out0, void* __restrict__ out1, void* __restrict__ out2,
    int M, int N, int K, int lda, int ldb, const float* __restrict__ xsrc)
{
    __shared__ short lds[16384];          // 32 KB: 4 x 4096 (A0,A1,B0,B1)
    short* As0 = lds;
    short* As1 = lds + 4096;
    short* Bs0 = lds + 8192;
    short* Bs1 = lds + 12288;

    const int tid = threadIdx.x;
    const int lane = tid & 63, w = tid >> 6;
    const int rl = lane & 15, g = lane >> 4;
    const int wr = w >> 1, wc = w & 1;
    const int nb = N >> 7;
    const int bm = blockIdx.x / nb, bn = blockIdx.x % nb;
    const int m0 = bm << 7, n0 = bn << 7;

    if (EPI == 3) { A += blockIdx.y << 8; BT += blockIdx.y << 8; }

    f32x4 acc[4][4];
#pragma unroll
    for (int m = 0; m < 4; ++m)
#pragma unroll
        for (int n = 0; n < 4; ++n) acc[m][n] = fzero();

    const short* ap = A + (long)(m0 + w * 32 + (lane >> 2)) * lda + ((lane & 3) << 3);
    const short* bp = BT + (long)(n0 + w * 32 + (lane >> 2)) * ldb + ((lane & 3) << 3);
    const int woff = w * 1024;

#define STAGE(dA, dB, kk) do { \
        gl16(ap + (kk), (dA) + woff); \
        gl16(ap + (kk) + 16 * lda, (dA) + woff + 512); \
        gl16(bp + (kk), (dB) + woff); \
        gl16(bp + (kk) + 16 * ldb, (dB) + woff + 512); } while (0)

    const int nt_ = K >> 5;
    STAGE(As0, Bs0, 0);
    __syncthreads();
    for (int t = 0; t < nt_; ++t) {
        const short* cA = (t & 1) ? As1 : As0;
        const short* cB = (t & 1) ? Bs1 : Bs0;
        short* nA = (t & 1) ? As0 : As1;
        short* nB = (t & 1) ? Bs0 : Bs1;
        if (t + 1 < nt_) STAGE(nA, nB, (t + 1) << 5);
        half8 af[4], bf[4];
#pragma unroll
        for (int m = 0; m < 4; ++m) af[m] = *(const half8*)&cA[(wr * 64 + m * 16 + rl) * 32 + g * 8];
#pragma unroll
        for (int n = 0; n < 4; ++n) bf[n] = *(const half8*)&cB[(wc * 64 + n * 16 + rl) * 32 + g * 8];
#pragma unroll
        for (int m = 0; m < 4; ++m)
#pragma unroll
            for (int n = 0; n < 4; ++n) acc[m][n] = MFMAH(af[m], bf[n], acc[m][n]);
        __syncthreads();
    }
#undef STAGE

    if (EPI == 1) {
        // sample into LDS tile [128][72] (stride 144B: 16B-aligned, bank-diagonal)
        const int d = n0 >> 9, c0 = (n0 >> 1) & 255;
#pragma unroll
        for (int m = 0; m < 4; ++m)
#pragma unroll
            for (int nt = 0; nt < 4; ++nt) {
                const int col = n0 + wc * 64 + nt * 16 + rl;
                float o4[4], po4[4];
                const float bb = b0[col];
#pragma unroll
                for (int j = 0; j < 4; ++j) o4[j] = tanhf(acc[m][nt][j] + bb);
#pragma unroll
                for (int j = 0; j < 4; ++j) po4[j] = __shfl_xor(o4[j], 1);
                const int jlo = (rl & 1) ? 2 : 0;
                const int cl = (wc * 64 + nt * 16 + rl) >> 1;
#pragma unroll
                for (int u = 0; u < 2; ++u) {
                    const int j = jlo + u;
                    float gx = (rl & 1) ? po4[j] : o4[j];
                    float gy = (rl & 1) ? o4[j] : po4[j];
                    gx = (gx + 1.f) * 127.5f;          // [0,255]
                    gy = (gy + 1.f) * 4095.5f;         // [0,8191]
                    float x0f = floorf(gx), y0f = floorf(gy);
                    float wx = gx - x0f, wy = gy - y0f;
                    int ix0 = (int)x0f, iy0 = (int)y0f;
                    int ix1 = min(ix0 + 1, 255), iy1 = min(iy0 + 1, 8191);
                    ix0 = max(min(ix0, 255), 0);
                    iy0 = max(min(iy0, 8191), 0);
                    ix1 = max(ix1, 0);
                    iy1 = max(iy1, 0);
                    const int rowl = wr * 64 + m * 16 + g * 4 + j;
                    const int b = (m0 + rowl) >> 10;
                    const float* xb = xsrc + b * 262144;
                    int r0 = (iy0 & 1023) << 8, r1 = (iy1 & 1023) << 8;
                    float v00 = xb[r0 + ix0], v01 = xb[r0 + ix1];
                    float v10 = xb[r1 + ix0], v11 = xb[r1 + ix1];
                    float r = v00 * (1.f - wy) * (1.f - wx) + v01 * (1.f - wy) * wx
                            + v10 * wy * (1.f - wx) + v11 * wy * wx;
                    lds[rowl * 72 + cl] = f2h(r);
                }
            }
        __syncthreads();
        // cooperative contiguous stores: 128 rows x 128B
        const int b = m0 >> 10, t0 = m0 & 1023;
        short* xo = (short*)out0 + ((long)(b * 8 + d) * 1024 + t0) * 256 + c0;
#pragma unroll
        for (int p = 0; p < 4; ++p) {
            int idx = p * 256 + tid, rowl = idx >> 3, ch = idx & 7;
            *(half8*)(xo + rowl * 256 + ch * 8) = *(const half8*)&lds[rowl * 72 + ch * 8];
        }
    } else if (EPI == 2) {
#pragma unroll
        for (int m = 0; m < 4; ++m)
#pragma unroll
            for (int nt = 0; nt < 4; ++nt) {
                const int col = n0 + wc * 64 + nt * 16 + rl;
#pragma unroll
                for (int j = 0; j < 4; ++j) {
                    const long grow = m0 + wr * 64 + m * 16 + g * 4 + j;
                    if (col < 256) {
                        ((short*)out0)[grow * 256 + col] = f2h((acc[m][nt][j] + b0[col]) * 0.125f);
                    } else if (col < 512) {
                        ((short*)out1)[grow * 256 + (col - 256)] = f2h(acc[m][nt][j] + b1[col - 256]);
                    } else {
                        int np = col - 512, hh = np >> 6, dd = np & 63;
                        long bh = grow >> 10, t = grow & 1023;
                        ((short*)out2)[((bh * 4 + hh) * 64 + dd) * 1024 + t] = f2h(acc[m][nt][j] + b2[np]);
                    }
                }
            }
    } else {  // EPI == 3: fp32 partial
        float* op = (float*)out0 + (long)blockIdx.y * M * N;
#pragma unroll
        for (int m = 0; m < 4; ++m)
#pragma unroll
            for (int nt = 0; nt < 4; ++nt) {
                const int col = n0 + wc * 64 + nt * 16 + rl;
#pragma unroll
                for (int j = 0; j < 4; ++j) {
                    const long grow = m0 + wr * 64 + m * 16 + g * 4 + j;
                    op[grow * N + col] = acc[m][nt][j];
                }
            }
    }
}

// sum split-K partials + bias -> fp32 out
__global__ void reduce_out_k(const float* __restrict__ p, const float* __restrict__ bo,
                             float* __restrict__ out) {
    int i = blockIdx.x * 256 + threadIdx.x;   // 524288
    float s = bo[i & 255];
#pragma unroll
    for (int ks = 0; ks < 8; ++ks) s += p[ks * 524288 + i];
    out[i] = s;
}

// ---------------- flash attention: swapped-operand, XCD-local K/V, reg dbuf prefetch ----------------
// block decode: bhh = bid & 63 -> the 8 q-blocks sharing one (bh,h)'s K/V have
// dispatch indices == bhh (mod 8) -> same XCD -> K/V L2-resident (2 MB/XCD).

__global__ __launch_bounds__(256) void attn_k(const short* __restrict__ q, const short* __restrict__ km,
                                              const short* __restrict__ vT, short* __restrict__ oc) {
    const int lane = threadIdx.x & 63, wv = threadIdx.x >> 6;
    const int l31 = lane & 31, hi = lane >> 5;
    const int bhh = blockIdx.x & 63;          // bh*4 + h  (XCD-local: idx%8 = bhh%8)
    const int bh = bhh >> 2, h = bhh & 3;
    const int q0 = (blockIdx.x >> 6) * 128 + wv * 32;

    const short* qb = q + (long)bh * 262144 + h * 64;
    const short* kb = km + (long)bh * 262144 + h * 64;
    const short* vb = vT + (long)bhh * 65536;

    half8 qf[4];
#pragma unroll
    for (int c = 0; c < 4; ++c)
        qf[c] = *(const half8*)(qb + (long)(q0 + l31) * 256 + c * 16 + hi * 8);

    float m_ = -1e30f, l_ = 0.f;
    f32x16 O0, O1;
#pragma unroll
    for (int r = 0; r < 16; ++r) { O0[r] = 0.f; O1[r] = 0.f; }

    half8 kA[4], vA[4], kB[4], vB[4];

    auto loadKV = [&](half8* KD, half8* VD, int kbase) {
#pragma unroll
        for (int c = 0; c < 4; ++c)
            KD[c] = *(const half8*)(kb + (long)(kbase + l31) * 256 + c * 16 + hi * 8);
        VD[0] = *(const half8*)(vb + (long)l31 * 1024 + kbase + hi * 8);
        VD[1] = *(const half8*)(vb + (long)(32 + l31) * 1024 + kbase + hi * 8);
        VD[2] = *(const half8*)(vb + (long)l31 * 1024 + kbase + 16 + hi * 8);
        VD[3] = *(const half8*)(vb + (long)(32 + l31) * 1024 + kbase + 16 + hi * 8);
    };

    auto tile = [&](const half8* KC, const half8* VC) {
        f32x16 S;
#pragma unroll
        for (int r = 0; r < 16; ++r) S[r] = 0.f;
#pragma unroll
        for (int c = 0; c < 4; ++c) S = MFMA32(KC[c], qf[c], S);
        float mx = S[0];
#pragma unroll
        for (int r = 1; r < 16; ++r) mx = fmaxf(mx, S[r]);
        mx = fmaxf(mx, __shfl_xor(mx, 32));
        if (__any(mx > m_)) {                 // defer-max
            float mn = fmaxf(m_, mx);
            float sc = __expf(m_ - mn);
            m_ = mn;
            l_ *= sc;
#pragma unroll
            for (int r = 0; r < 16; ++r) { O0[r] *= sc; O1[r] *= sc; }
        }
        float p[16];
        float rs = 0.f;
#pragma unroll
        for (int r = 0; r < 16; ++r) { p[r] = __expf(S[r] - m_); rs += p[r]; }
        rs += __shfl_xor(rs, 32);
        l_ += rs;
        half8 PA[2];
#pragma unroll
        for (int c = 0; c < 2; ++c) {
            const int o = c * 8;
            unsigned a0 = __builtin_bit_cast(unsigned, __builtin_amdgcn_cvt_pkrtz(p[o + 0], p[o + 1]));
            unsigned b0v = __builtin_bit_cast(unsigned, __builtin_amdgcn_cvt_pkrtz(p[o + 4], p[o + 5]));
            unsigned a1 = __builtin_bit_cast(unsigned, __builtin_amdgcn_cvt_pkrtz(p[o + 2], p[o + 3]));
            unsigned b1v = __builtin_bit_cast(unsigned, __builtin_amdgcn_cvt_pkrtz(p[o + 6], p[o + 7]));
            uint2v r0 = __builtin_amdgcn_permlane32_swap(a0, b0v, false, false);
            uint2v r1 = __builtin_amdgcn_permlane32_swap(a1, b1v, false, false);
            uint4v wpk = {r0[0], r1[0], r0[1], r1[1]};
            PA[c] = __builtin_bit_cast(half8, wpk);
        }
        O0 = MFMA32(VC[0], PA[0], O0);
        O1 = MFMA32(VC[1], PA[0], O1);
        O0 = MFMA32(VC[2], PA[1], O0);
        O1 = MFMA32(VC[3], PA[1], O1);
    };

    loadKV(kA, vA, 0);
    for (int kk = 0; kk < 32; kk += 2) {
        loadKV(kB, vB, (kk + 1) * 32);       // prefetch next tile before computing current
        tile(kA, vA);
        if (kk + 2 < 32) loadKV(kA, vA, (kk + 2) * 32);
        tile(kB, vB);
    }

    const float inv = 1.f / l_;
    const int b = bh >> 3, d = bh & 7;
    const int t = q0 + l31;
    short* ob = oc + ((long)(b * 1024 + t) * 8 + d) * 256 + h * 64;
#pragma unroll
    for (int rr = 0; rr < 8; ++rr) {
        int dvb = (rr & 1) * 2 + 8 * (rr >> 1) + 4 * hi;
        unsigned u0 = (unsigned short)f2h(O0[2 * rr] * inv) | ((unsigned)(unsigned short)f2h(O0[2 * rr + 1] * inv) << 16);
        unsigned u1 = (unsigned short)f2h(O1[2 * rr] * inv) | ((unsigned)(unsigned short)f2h(O1[2 * rr + 1] * inv) << 16);
        *(unsigned*)(ob + dvb) = u0;
        *(unsigned*)(ob + 32 + dvb) = u1;
    }
}

// ---------------- launch ----------------

extern "C" void kernel_launch(void* const* d_in, const int* in_sizes, int n_in,
                              void* d_out, int out_size, void* d_ws, size_t ws_size,
                              hipStream_t stream) {
    const float* x     = (const float*)d_in[0];
    const float* Woff1 = (const float*)d_in[1];
    const float* boff1 = (const float*)d_in[2];
    const float* Woff2 = (const float*)d_in[3];
    const float* boff2 = (const float*)d_in[4];
    const float* Wq    = (const float*)d_in[5];
    const float* bq    = (const float*)d_in[6];
    const float* Wk    = (const float*)d_in[7];
    const float* bk    = (const float*)d_in[8];
    const float* Wv    = (const float*)d_in[9];
    const float* bv    = (const float*)d_in[10];
    const float* Wo    = (const float*)d_in[11];
    const float* bo    = (const float*)d_in[12];

    char* ws = (char*)d_ws;
    short* hsplit = (short*)(ws + 0);             // 2048*768*2  = 3,145,728
    short* B2T    = (short*)(ws + 3145728);       // 4096*768*2  = 6,291,456 (end 9,437,184)
    short* cat    = (short*)(ws + 0);             // 2048*2048*2 = 8,388,608 (alias; B2T/hsplit dead)
    short* Wtqkv  = (short*)(ws + 9437184);       // 768*256*2   =   393,216
    short* WtoT   = (short*)(ws + 9830400);       // 256*2048*2  = 1,048,576
    short* xs     = (short*)(ws + 10878976);      // 16384*256*2 = 8,388,608
    short* qbuf   = (short*)(ws + 19267584);      // 8,388,608
    short* kbuf   = (short*)(ws + 27656192);      // 8,388,608
    short* vT     = (short*)(ws + 36044800);      // 8,388,608  (end 44,433,408)
    float* parts  = (float*)(ws + 44433408);      // 8*2048*256*4 = 16,777,216 (end 61,210,624)

    // prep
    split_w2_k<<<256, 256, 0, stream>>>(Woff2, B2T);
    qkv_prep_k<<<768, 256, 0, stream>>>(Wq, Wk, Wv, Wtqkv);
    wo_prep_k<<<2048, 256, 0, stream>>>(Wo, WtoT);

    // offset network stage 1: exact fp32 + gelu + fp16 split
    gemm1_k<<<128, 256, 0, stream>>>(x, Woff1, boff1, hsplit);

    // stage 2 (f16 3-term) + fused tanh + bilinear resampling
    gemm128<1><<<(2048 / 128) * (4096 / 128), 256, 0, stream>>>(
        hsplit, B2T, boff2, nullptr, nullptr, xs, nullptr, nullptr, 2048, 4096, 768, 768, 768, x);

    // qkv projections (V transposed per (bh,h); q pre-scaled by 0.125)
    gemm128<2><<<(16384 / 128) * (768 / 128), 256, 0, stream>>>(
        xs, Wtqkv, bq, bk, bv, qbuf, kbuf, vT, 16384, 768, 256, 256, 256, nullptr);

    // attention (swapped-operand, XCD-local K/V, reg-dbuf prefetch)
    attn_k<<<512, 256, 0, stream>>>(qbuf, kbuf, vT, cat);

    // output projection: split-K=8 partials + reduce
    gemm128<3><<<dim3((2048 / 128) * (256 / 128), 8), 256, 0, stream>>>(
        cat, WtoT, nullptr, nullptr, nullptr, parts, nullptr, nullptr, 2048, 256, 256, 2048, 2048, nullptr);
    reduce_out_k<<<2048, 256, 0, stream>>>(parts, bo, (float*)d_out);
}

// Round 8
// 172.033 us; speedup vs baseline: 1.6756x; 1.1765x over previous
//
#include <hip/hip_runtime.h>
#include <hip/hip_bf16.h>

typedef __attribute__((ext_vector_type(8))) _Float16 half8;   // 8 f16 = 4 VGPRs
typedef __attribute__((ext_vector_type(4))) float f32x4;
typedef __attribute__((ext_vector_type(16))) float f32x16;
typedef __attribute__((ext_vector_type(2))) unsigned uint2v;
typedef __attribute__((ext_vector_type(4))) unsigned uint4v;

#define MFMAH(a, b, c) __builtin_amdgcn_mfma_f32_16x16x32_f16((a), (b), (c), 0, 0, 0)
#define MFMA32(a, b, c) __builtin_amdgcn_mfma_f32_32x32x16_f16((a), (b), (c), 0, 0, 0)

__device__ __forceinline__ short f2h(float v) { _Float16 h = (_Float16)v; return __builtin_bit_cast(short, h); }
__device__ __forceinline__ f32x4 fzero() { f32x4 z = {0.f, 0.f, 0.f, 0.f}; return z; }
__device__ __forceinline__ float u2f(unsigned u) { return __builtin_bit_cast(float, u); }
__device__ __forceinline__ unsigned f2u(float f) { return __builtin_bit_cast(unsigned, f); }

__device__ __forceinline__ void gl16(const void* g, void* l) {
    // async global->LDS, 16B/lane; LDS dest = wave-uniform base + lane*16
    __builtin_amdgcn_global_load_lds((const __attribute__((address_space(1))) unsigned*)g,
                                     (__attribute__((address_space(3))) unsigned*)l, 16, 0, 0);
}

__device__ __forceinline__ float gelu_tanh(float v) {
    float u = 0.7978845608028654f * (v + 0.044715f * v * v * v);
    return 0.5f * v * (1.f + tanhf(u));
}

// ---------------- prep kernels ----------------

// W_off2 (256,4096) -> B2T (4096,768) f16 [w1|w1|w2], LDS-tiled transpose
__global__ __launch_bounds__(256) void split_w2_k(const float* __restrict__ w, short* __restrict__ dst) {
    __shared__ float t[64][65];
    const int tid = threadIdx.x;
    const int bk = blockIdx.x >> 6, bn = blockIdx.x & 63;    // 4 x 64 blocks
    const int k0 = bk * 64, n0 = bn * 64;
#pragma unroll
    for (int p = 0; p < 16; ++p) {
        int idx = p * 256 + tid, r = idx >> 6, c = idx & 63;
        t[r][c] = w[(long)(k0 + r) * 4096 + n0 + c];
    }
    __syncthreads();
#pragma unroll
    for (int p = 0; p < 16; ++p) {
        int idx = p * 256 + tid, nr = idx >> 6, kc = idx & 63;
        float v = t[kc][nr];
        _Float16 w1 = (_Float16)v;
        _Float16 w2 = (_Float16)(v - (float)w1);
        long base = (long)(n0 + nr) * 768 + k0 + kc;
        dst[base]       = __builtin_bit_cast(short, w1);
        dst[base + 256] = __builtin_bit_cast(short, w1);
        dst[base + 512] = __builtin_bit_cast(short, w2);
    }
}

__global__ void qkv_prep_k(const float* __restrict__ Wq, const float* __restrict__ Wk,
                           const float* __restrict__ Wv, short* __restrict__ dst) {
    int i = blockIdx.x * 256 + threadIdx.x;        // 768*256
    int n = i >> 8, k = i & 255;
    const float* s = (n < 256) ? Wq : (n < 512) ? Wk : Wv;
    dst[i] = f2h(s[k * 256 + (n & 255)]);
}

__global__ void wo_prep_k(const float* __restrict__ Wo, short* __restrict__ dst) {
    int i = blockIdx.x * 256 + threadIdx.x;        // 256*2048
    int n = i >> 11, k = i & 2047;
    dst[i] = f2h(Wo[k * 256 + n]);
}

// ---------------- GEMM1: exact fp32, fused gelu + fp16 hi/lo split ----------------

__global__ __launch_bounds__(256) void gemm1_k(const float* __restrict__ x, const float* __restrict__ W,
                                               const float* __restrict__ bias, short* __restrict__ hs) {
    __shared__ float As[64][17];
    __shared__ float Bs[16][68];
    const int tid = threadIdx.x;
    const int bm = blockIdx.x >> 2, bn = blockIdx.x & 3;     // 32 x 4
    const int m0 = bm * 64, n0 = bn * 64;
    const int ty = tid >> 4, tx = tid & 15;
    float acc[4][4] = {};
    const int ar = tid >> 2, ak = (tid & 3) << 2;
    const int bk = tid >> 4, bc = (tid & 15) << 2;

    for (int k0 = 0; k0 < 256; k0 += 16) {
        __syncthreads();
        float4 av = *(const float4*)(x + (m0 + ar) * 256 + k0 + ak);
        As[ar][ak + 0] = av.x; As[ar][ak + 1] = av.y; As[ar][ak + 2] = av.z; As[ar][ak + 3] = av.w;
        *(float4*)&Bs[bk][bc] = *(const float4*)(W + (k0 + bk) * 256 + n0 + bc);
        __syncthreads();
#pragma unroll
        for (int kk = 0; kk < 16; ++kk) {
            float a_[4], b_[4];
#pragma unroll
            for (int i = 0; i < 4; ++i) a_[i] = As[ty * 4 + i][kk];
            *(float4*)b_ = *(const float4*)&Bs[kk][tx * 4];
#pragma unroll
            for (int i = 0; i < 4; ++i)
#pragma unroll
                for (int j = 0; j < 4; ++j) acc[i][j] += a_[i] * b_[j];
        }
    }
#pragma unroll
    for (int i = 0; i < 4; ++i) {
        int row = m0 + ty * 4 + i;
#pragma unroll
        for (int j = 0; j < 4; ++j) {
            int col = n0 + tx * 4 + j;
            float v = gelu_tanh(acc[i][j] + bias[col]);
            _Float16 h1 = (_Float16)v;
            _Float16 h2 = (_Float16)(v - (float)h1);
            hs[row * 768 + col]       = __builtin_bit_cast(short, h1);
            hs[row * 768 + 256 + col] = __builtin_bit_cast(short, h2);
            hs[row * 768 + 512 + col] = __builtin_bit_cast(short, h1);
        }
    }
}

// ---------------- 128x128 MFMA GEMM, double-buffered global_load_lds ----------------
// EPI 1: +bias, tanh -> fused bilinear grid-sample, LDS-staged contiguous stores
// EPI 2: qkv scatter (q*0.125*log2e; K/V into fragment-ordered tiled layouts)
// EPI 3: fp32 split-K partial (blockIdx.y = ks)

template <int EPI>
__global__ __launch_bounds__(256, 2) void gemm128(
    const short* __restrict__ A, const short* __restrict__ BT,
    const float* __restrict__ b0, const float* __restrict__ b1, const float* __restrict__ b2,
    void* __restrict__ out0, void* __restrict__ out1, void* __restrict__ out2,
    int M, int N, int K, int lda, int ldb, const float* __restrict__ xsrc)
{
    __shared__ short lds[16384];          // 32 KB: 4 x 4096 (A0,A1,B0,B1)
    short* As0 = lds;
    short* As1 = lds + 4096;
    short* Bs0 = lds + 8192;
    short* Bs1 = lds + 12288;

    const int tid = threadIdx.x;
    const int lane = tid & 63, w = tid >> 6;
    const int rl = lane & 15, g = lane >> 4;
    const int wr = w >> 1, wc = w & 1;
    const int nb = N >> 7;
    const int bm = blockIdx.x / nb, bn = blockIdx.x % nb;
    const int m0 = bm << 7, n0 = bn << 7;

    if (EPI == 3) { A += blockIdx.y << 8; BT += blockIdx.y << 8; }

    f32x4 acc[4][4];
#pragma unroll
    for (int m = 0; m < 4; ++m)
#pragma unroll
        for (int n = 0; n < 4; ++n) acc[m][n] = fzero();

    const short* ap = A + (long)(m0 + w * 32 + (lane >> 2)) * lda + ((lane & 3) << 3);
    const short* bp = BT + (long)(n0 + w * 32 + (lane >> 2)) * ldb + ((lane & 3) << 3);
    const int woff = w * 1024;

#define STAGE(dA, dB, kk) do { \
        gl16(ap + (kk), (dA) + woff); \
        gl16(ap + (kk) + 16 * lda, (dA) + woff + 512); \
        gl16(bp + (kk), (dB) + woff); \
        gl16(bp + (kk) + 16 * ldb, (dB) + woff + 512); } while (0)

    const int nt_ = K >> 5;
    STAGE(As0, Bs0, 0);
    __syncthreads();
    for (int t = 0; t < nt_; ++t) {
        const short* cA = (t & 1) ? As1 : As0;
        const short* cB = (t & 1) ? Bs1 : Bs0;
        short* nA = (t & 1) ? As0 : As1;
        short* nB = (t & 1) ? Bs0 : Bs1;
        if (t + 1 < nt_) STAGE(nA, nB, (t + 1) << 5);
        half8 af[4], bf[4];
#pragma unroll
        for (int m = 0; m < 4; ++m) af[m] = *(const half8*)&cA[(wr * 64 + m * 16 + rl) * 32 + g * 8];
#pragma unroll
        for (int n = 0; n < 4; ++n) bf[n] = *(const half8*)&cB[(wc * 64 + n * 16 + rl) * 32 + g * 8];
#pragma unroll
        for (int m = 0; m < 4; ++m)
#pragma unroll
            for (int n = 0; n < 4; ++n) acc[m][n] = MFMAH(af[m], bf[n], acc[m][n]);
        __syncthreads();
    }
#undef STAGE

    if (EPI == 1) {
        // sample into LDS tile [128][72] (stride 144B: 16B-aligned, bank-diagonal)
        const int d = n0 >> 9, c0 = (n0 >> 1) & 255;
#pragma unroll
        for (int m = 0; m < 4; ++m)
#pragma unroll
            for (int nt = 0; nt < 4; ++nt) {
                const int col = n0 + wc * 64 + nt * 16 + rl;
                float o4[4], po4[4];
                const float bb = b0[col];
#pragma unroll
                for (int j = 0; j < 4; ++j) o4[j] = tanhf(acc[m][nt][j] + bb);
#pragma unroll
                for (int j = 0; j < 4; ++j) po4[j] = __shfl_xor(o4[j], 1);
                const int jlo = (rl & 1) ? 2 : 0;
                const int cl = (wc * 64 + nt * 16 + rl) >> 1;
#pragma unroll
                for (int u = 0; u < 2; ++u) {
                    const int j = jlo + u;
                    float gx = (rl & 1) ? po4[j] : o4[j];
                    float gy = (rl & 1) ? o4[j] : po4[j];
                    gx = (gx + 1.f) * 127.5f;          // [0,255]
                    gy = (gy + 1.f) * 4095.5f;         // [0,8191]
                    float x0f = floorf(gx), y0f = floorf(gy);
                    float wx = gx - x0f, wy = gy - y0f;
                    int ix0 = (int)x0f, iy0 = (int)y0f;
                    int ix1 = min(ix0 + 1, 255), iy1 = min(iy0 + 1, 8191);
                    ix0 = max(min(ix0, 255), 0);
                    iy0 = max(min(iy0, 8191), 0);
                    ix1 = max(ix1, 0);
                    iy1 = max(iy1, 0);
                    const int rowl = wr * 64 + m * 16 + g * 4 + j;
                    const int b = (m0 + rowl) >> 10;
                    const float* xb = xsrc + b * 262144;
                    int r0 = (iy0 & 1023) << 8, r1 = (iy1 & 1023) << 8;
                    float v00 = xb[r0 + ix0], v01 = xb[r0 + ix1];
                    float v10 = xb[r1 + ix0], v11 = xb[r1 + ix1];
                    float r = v00 * (1.f - wy) * (1.f - wx) + v01 * (1.f - wy) * wx
                            + v10 * wy * (1.f - wx) + v11 * wy * wx;
                    lds[rowl * 72 + cl] = f2h(r);
                }
            }
        __syncthreads();
        // cooperative contiguous stores: 128 rows x 128B
        const int b = m0 >> 10, t0 = m0 & 1023;
        short* xo = (short*)out0 + ((long)(b * 8 + d) * 1024 + t0) * 256 + c0;
#pragma unroll
        for (int p = 0; p < 4; ++p) {
            int idx = p * 256 + tid, rowl = idx >> 3, ch = idx & 7;
            *(half8*)(xo + rowl * 256 + ch * 8) = *(const half8*)&lds[rowl * 72 + ch * 8];
        }
    } else if (EPI == 2) {
#pragma unroll
        for (int m = 0; m < 4; ++m)
#pragma unroll
            for (int nt = 0; nt < 4; ++nt) {
                const int col = n0 + wc * 64 + nt * 16 + rl;
#pragma unroll
                for (int j = 0; j < 4; ++j) {
                    const long grow = m0 + wr * 64 + m * 16 + g * 4 + j;
                    const int bh = (int)(grow >> 10), t = (int)(grow & 1023);
                    if (col < 256) {
                        // q scaled by 0.125*log2(e): attention softmax runs in exp2 domain
                        ((short*)out0)[grow * 256 + col] = f2h((acc[m][nt][j] + b0[col]) * 0.18033688011112042f);
                    } else if (col < 512) {
                        // K -> fragment-ordered tile: slot ((bhh*32+kk)*4+c)*64 + hi*32+l31, elem e
                        int nk = col - 256, h = nk >> 6, dd = nk & 63;
                        int kk = t >> 5, l31t = t & 31;
                        int c = dd >> 4, hi2 = (dd >> 3) & 1, e = dd & 7;
                        long slot = ((((long)(bh * 4 + h) * 32 + kk) * 4 + c) * 64 + hi2 * 32 + l31t) * 8 + e;
                        ((short*)out1)[slot] = f2h(acc[m][nt][j] + b1[nk]);
                    } else {
                        // V -> fragment-ordered tile: c = (key-chunk)*2 + d-half
                        int np = col - 512, h = np >> 6, d = np & 63;
                        int kk = t >> 5;
                        int chi = (t >> 4) & 1, hi2 = (t >> 3) & 1, e = t & 7;
                        int c = chi * 2 + (d >> 5);
                        long slot = ((((long)(bh * 4 + h) * 32 + kk) * 4 + c) * 64 + hi2 * 32 + (d & 31)) * 8 + e;
                        ((short*)out2)[slot] = f2h(acc[m][nt][j] + b2[np]);
                    }
                }
            }
    } else {  // EPI == 3: fp32 partial
        float* op = (float*)out0 + (long)blockIdx.y * M * N;
#pragma unroll
        for (int m = 0; m < 4; ++m)
#pragma unroll
            for (int nt = 0; nt < 4; ++nt) {
                const int col = n0 + wc * 64 + nt * 16 + rl;
#pragma unroll
                for (int j = 0; j < 4; ++j) {
                    const long grow = m0 + wr * 64 + m * 16 + g * 4 + j;
                    op[grow * N + col] = acc[m][nt][j];
                }
            }
    }
}

// sum split-K partials + bias -> fp32 out
__global__ void reduce_out_k(const float* __restrict__ p, const float* __restrict__ bo,
                             float* __restrict__ out) {
    int i = blockIdx.x * 256 + threadIdx.x;   // 524288
    float s = bo[i & 255];
#pragma unroll
    for (int ks = 0; ks < 8; ++ks) s += p[ks * 524288 + i];
    out[i] = s;
}

// ---------------- flash attention: LDS-staged coalesced K/V, swapped-operand ----------------
// K/V stored in fragment-ordered 4KB tiles; block stages K+V tile (8KB) via
// global_load_lds into a double buffer shared by all 4 waves; fragment reads
// are lane-major (conflict-free). Softmax in exp2 domain, permlane cross-half.

__global__ __launch_bounds__(256) void attn_k(const short* __restrict__ q, const short* __restrict__ kc,
                                              const short* __restrict__ vc, short* __restrict__ oc) {
    __shared__ short kv[8192];   // 16KB: buf b at b*4096 shorts: [K 2048 | V 2048]
    const int tid = threadIdx.x;
    const int lane = tid & 63, w = tid >> 6;
    const int l31 = lane & 31, hi = lane >> 5;
    const int bhh = blockIdx.x & 63;          // XCD-local: idx%8 = bhh%8
    const int bh = bhh >> 2, h = bhh & 3;
    const int q0 = (blockIdx.x >> 6) * 128 + w * 32;

    const short* qb = q + (long)bh * 262144 + h * 64;
    const short* kt = kc + (long)bhh * 65536;   // 32 tiles x 2048 shorts
    const short* vt = vc + (long)bhh * 65536;

    half8 qf[4];
#pragma unroll
    for (int c = 0; c < 4; ++c)
        qf[c] = *(const half8*)(qb + (long)(q0 + l31) * 256 + c * 16 + hi * 8);

    float m_ = -1e30f, l_ = 0.f;
    f32x16 O0, O1;
#pragma unroll
    for (int r = 0; r < 16; ++r) { O0[r] = 0.f; O1[r] = 0.f; }

    const int sw = w * 512 + lane * 8;        // per-lane src offset within a tile

#define KVSTAGE(kk, b) do { \
        gl16(kt + (kk) * 2048 + sw, &kv[(b) * 4096 + w * 512]); \
        gl16(vt + (kk) * 2048 + sw, &kv[(b) * 4096 + 2048 + w * 512]); } while (0)

    KVSTAGE(0, 0);
    __syncthreads();
    for (int kk = 0; kk < 32; ++kk) {
        const int b = kk & 1;
        if (kk + 1 < 32) KVSTAGE(kk + 1, b ^ 1);
        half8 KD[4], VD[4];
#pragma unroll
        for (int c = 0; c < 4; ++c) {
            KD[c] = *(const half8*)&kv[b * 4096 + c * 512 + lane * 8];
            VD[c] = *(const half8*)&kv[b * 4096 + 2048 + c * 512 + lane * 8];
        }
        f32x16 S;
#pragma unroll
        for (int r = 0; r < 16; ++r) S[r] = 0.f;
#pragma unroll
        for (int c = 0; c < 4; ++c) S = MFMA32(KD[c], qf[c], S);
        // tree max over 16, then cross-half via permlane32_swap
        float t8[8];
#pragma unroll
        for (int r = 0; r < 8; ++r) t8[r] = fmaxf(S[2 * r], S[2 * r + 1]);
        float mx = fmaxf(fmaxf(fmaxf(t8[0], t8[1]), fmaxf(t8[2], t8[3])),
                         fmaxf(fmaxf(t8[4], t8[5]), fmaxf(t8[6], t8[7])));
        uint2v sp = __builtin_amdgcn_permlane32_swap(f2u(mx), f2u(mx), false, false);
        mx = fmaxf(u2f(sp[0]), u2f(sp[1]));
        if (__any(mx > m_ + 8.f)) {           // defer-max THR=8 (log2 units)
            float mn = fmaxf(m_, mx);
            float sc = exp2f(m_ - mn);
            m_ = mn;
            l_ *= sc;
#pragma unroll
            for (int r = 0; r < 16; ++r) { O0[r] *= sc; O1[r] *= sc; }
        }
        float p[16];
#pragma unroll
        for (int r = 0; r < 16; ++r) p[r] = exp2f(S[r] - m_);
        float s8[8];
#pragma unroll
        for (int r = 0; r < 8; ++r) s8[r] = p[2 * r] + p[2 * r + 1];
        float rs = (((s8[0] + s8[1]) + (s8[2] + s8[3])) + ((s8[4] + s8[5]) + (s8[6] + s8[7])));
        uint2v sq = __builtin_amdgcn_permlane32_swap(f2u(rs), f2u(rs), false, false);
        rs = u2f(sq[0]) + u2f(sq[1]);
        l_ += rs;
        // pack P^T fragments (cvt_pkrtz + permlane32_swap)
        half8 PA[2];
#pragma unroll
        for (int c = 0; c < 2; ++c) {
            const int o = c * 8;
            unsigned a0 = f2u(__builtin_bit_cast(float, __builtin_amdgcn_cvt_pkrtz(p[o + 0], p[o + 1])));
            unsigned b0v = f2u(__builtin_bit_cast(float, __builtin_amdgcn_cvt_pkrtz(p[o + 4], p[o + 5])));
            unsigned a1 = f2u(__builtin_bit_cast(float, __builtin_amdgcn_cvt_pkrtz(p[o + 2], p[o + 3])));
            unsigned b1v = f2u(__builtin_bit_cast(float, __builtin_amdgcn_cvt_pkrtz(p[o + 6], p[o + 7])));
            uint2v r0 = __builtin_amdgcn_permlane32_swap(a0, b0v, false, false);
            uint2v r1 = __builtin_amdgcn_permlane32_swap(a1, b1v, false, false);
            uint4v wpk = {r0[0], r1[0], r0[1], r1[1]};
            PA[c] = __builtin_bit_cast(half8, wpk);
        }
        O0 = MFMA32(VD[0], PA[0], O0);
        O1 = MFMA32(VD[1], PA[0], O1);
        O0 = MFMA32(VD[2], PA[1], O0);
        O1 = MFMA32(VD[3], PA[1], O1);
        __syncthreads();
    }
#undef KVSTAGE

    const float inv = 1.f / l_;
    const int b = bh >> 3, d = bh & 7;
    const int t = q0 + l31;
    short* ob = oc + ((long)(b * 1024 + t) * 8 + d) * 256 + h * 64;
#pragma unroll
    for (int rr = 0; rr < 8; ++rr) {
        int dvb = (rr & 1) * 2 + 8 * (rr >> 1) + 4 * hi;
        unsigned u0 = (unsigned short)f2h(O0[2 * rr] * inv) | ((unsigned)(unsigned short)f2h(O0[2 * rr + 1] * inv) << 16);
        unsigned u1 = (unsigned short)f2h(O1[2 * rr] * inv) | ((unsigned)(unsigned short)f2h(O1[2 * rr + 1] * inv) << 16);
        *(unsigned*)(ob + dvb) = u0;
        *(unsigned*)(ob + 32 + dvb) = u1;
    }
}

// ---------------- launch ----------------

extern "C" void kernel_launch(void* const* d_in, const int* in_sizes, int n_in,
                              void* d_out, int out_size, void* d_ws, size_t ws_size,
                              hipStream_t stream) {
    const float* x     = (const float*)d_in[0];
    const float* Woff1 = (const float*)d_in[1];
    const float* boff1 = (const float*)d_in[2];
    const float* Woff2 = (const float*)d_in[3];
    const float* boff2 = (const float*)d_in[4];
    const float* Wq    = (const float*)d_in[5];
    const float* bq    = (const float*)d_in[6];
    const float* Wk    = (const float*)d_in[7];
    const float* bk    = (const float*)d_in[8];
    const float* Wv    = (const float*)d_in[9];
    const float* bv    = (const float*)d_in[10];
    const float* Wo    = (const float*)d_in[11];
    const float* bo    = (const float*)d_in[12];

    char* ws = (char*)d_ws;
    short* hsplit = (short*)(ws + 0);             // 2048*768*2  = 3,145,728
    short* B2T    = (short*)(ws + 3145728);       // 4096*768*2  = 6,291,456 (end 9,437,184)
    short* cat    = (short*)(ws + 0);             // 2048*2048*2 = 8,388,608 (alias; B2T/hsplit dead)
    short* Wtqkv  = (short*)(ws + 9437184);       // 768*256*2   =   393,216
    short* WtoT   = (short*)(ws + 9830400);       // 256*2048*2  = 1,048,576
    short* xs     = (short*)(ws + 10878976);      // 16384*256*2 = 8,388,608
    short* qbuf   = (short*)(ws + 19267584);      // 8,388,608
    short* kcoal  = (short*)(ws + 27656192);      // 8,388,608 (64 bhh x 32 tiles x 4KB)
    short* vcoal  = (short*)(ws + 36044800);      // 8,388,608  (end 44,433,408)
    float* parts  = (float*)(ws + 44433408);      // 8*2048*256*4 = 16,777,216 (end 61,210,624)

    // prep
    split_w2_k<<<256, 256, 0, stream>>>(Woff2, B2T);
    qkv_prep_k<<<768, 256, 0, stream>>>(Wq, Wk, Wv, Wtqkv);
    wo_prep_k<<<2048, 256, 0, stream>>>(Wo, WtoT);

    // offset network stage 1: exact fp32 + gelu + fp16 split
    gemm1_k<<<128, 256, 0, stream>>>(x, Woff1, boff1, hsplit);

    // stage 2 (f16 3-term) + fused tanh + bilinear resampling
    gemm128<1><<<(2048 / 128) * (4096 / 128), 256, 0, stream>>>(
        hsplit, B2T, boff2, nullptr, nullptr, xs, nullptr, nullptr, 2048, 4096, 768, 768, 768, x);

    // qkv projections (q pre-scaled into exp2 domain; K/V fragment-ordered)
    gemm128<2><<<(16384 / 128) * (768 / 128), 256, 0, stream>>>(
        xs, Wtqkv, bq, bk, bv, qbuf, kcoal, vcoal, 16384, 768, 256, 256, 256, nullptr);

    // attention (LDS-staged coalesced K/V, swapped-operand)
    attn_k<<<512, 256, 0, stream>>>(qbuf, kcoal, vcoal, cat);

    // output projection: split-K=8 partials + reduce
    gemm128<3><<<dim3((2048 / 128) * (256 / 128), 8), 256, 0, stream>>>(
        cat, WtoT, nullptr, nullptr, nullptr, parts, nullptr, nullptr, 2048, 256, 256, 2048, 2048, nullptr);
    reduce_out_k<<<2048, 256, 0, stream>>>(parts, bo, (float*)d_out);
}

// Round 9
// 164.985 us; speedup vs baseline: 1.7472x; 1.0427x over previous
//
#include <hip/hip_runtime.h>
#include <hip/hip_bf16.h>

typedef __attribute__((ext_vector_type(8))) _Float16 half8;   // 8 f16 = 4 VGPRs
typedef __attribute__((ext_vector_type(4))) float f32x4;
typedef __attribute__((ext_vector_type(16))) float f32x16;
typedef __attribute__((ext_vector_type(2))) unsigned uint2v;
typedef __attribute__((ext_vector_type(4))) unsigned uint4v;

#define MFMAH(a, b, c) __builtin_amdgcn_mfma_f32_16x16x32_f16((a), (b), (c), 0, 0, 0)
#define MFMA32(a, b, c) __builtin_amdgcn_mfma_f32_32x32x16_f16((a), (b), (c), 0, 0, 0)

__device__ __forceinline__ short f2h(float v) { _Float16 h = (_Float16)v; return __builtin_bit_cast(short, h); }
__device__ __forceinline__ f32x4 fzero() { f32x4 z = {0.f, 0.f, 0.f, 0.f}; return z; }
__device__ __forceinline__ float u2f(unsigned u) { return __builtin_bit_cast(float, u); }
__device__ __forceinline__ unsigned f2u(float f) { return __builtin_bit_cast(unsigned, f); }

__device__ __forceinline__ void gl16(const void* g, void* l) {
    // async global->LDS, 16B/lane; LDS dest = wave-uniform base + lane*16
    __builtin_amdgcn_global_load_lds((const __attribute__((address_space(1))) unsigned*)g,
                                     (__attribute__((address_space(3))) unsigned*)l, 16, 0, 0);
}

__device__ __forceinline__ float gelu_tanh(float v) {
    float u = 0.7978845608028654f * (v + 0.044715f * v * v * v);
    return 0.5f * v * (1.f + tanhf(u));
}

// ---------------- prep kernels ----------------

// W_off2 (256,4096) -> B2T (4096,768) f16 [w1|w1|w2], LDS-tiled transpose
__global__ __launch_bounds__(256) void split_w2_k(const float* __restrict__ w, short* __restrict__ dst) {
    __shared__ float t[64][65];
    const int tid = threadIdx.x;
    const int bk = blockIdx.x >> 6, bn = blockIdx.x & 63;    // 4 x 64 blocks
    const int k0 = bk * 64, n0 = bn * 64;
#pragma unroll
    for (int p = 0; p < 16; ++p) {
        int idx = p * 256 + tid, r = idx >> 6, c = idx & 63;
        t[r][c] = w[(long)(k0 + r) * 4096 + n0 + c];
    }
    __syncthreads();
#pragma unroll
    for (int p = 0; p < 16; ++p) {
        int idx = p * 256 + tid, nr = idx >> 6, kc = idx & 63;
        float v = t[kc][nr];
        _Float16 w1 = (_Float16)v;
        _Float16 w2 = (_Float16)(v - (float)w1);
        long base = (long)(n0 + nr) * 768 + k0 + kc;
        dst[base]       = __builtin_bit_cast(short, w1);
        dst[base + 256] = __builtin_bit_cast(short, w1);
        dst[base + 512] = __builtin_bit_cast(short, w2);
    }
}

__global__ void qkv_prep_k(const float* __restrict__ Wq, const float* __restrict__ Wk,
                           const float* __restrict__ Wv, short* __restrict__ dst) {
    int i = blockIdx.x * 256 + threadIdx.x;        // 768*256
    int n = i >> 8, k = i & 255;
    const float* s = (n < 256) ? Wq : (n < 512) ? Wk : Wv;
    dst[i] = f2h(s[k * 256 + (n & 255)]);
}

__global__ void wo_prep_k(const float* __restrict__ Wo, short* __restrict__ dst) {
    int i = blockIdx.x * 256 + threadIdx.x;        // 256*2048
    int n = i >> 11, k = i & 2047;
    dst[i] = f2h(Wo[k * 256 + n]);
}

// ---------------- GEMM1: exact fp32, fused gelu + fp16 hi/lo split ----------------

__global__ __launch_bounds__(256) void gemm1_k(const float* __restrict__ x, const float* __restrict__ W,
                                               const float* __restrict__ bias, short* __restrict__ hs) {
    __shared__ float As[64][17];
    __shared__ float Bs[16][68];
    const int tid = threadIdx.x;
    const int bm = blockIdx.x >> 2, bn = blockIdx.x & 3;     // 32 x 4
    const int m0 = bm * 64, n0 = bn * 64;
    const int ty = tid >> 4, tx = tid & 15;
    float acc[4][4] = {};
    const int ar = tid >> 2, ak = (tid & 3) << 2;
    const int bk = tid >> 4, bc = (tid & 15) << 2;

    for (int k0 = 0; k0 < 256; k0 += 16) {
        __syncthreads();
        float4 av = *(const float4*)(x + (m0 + ar) * 256 + k0 + ak);
        As[ar][ak + 0] = av.x; As[ar][ak + 1] = av.y; As[ar][ak + 2] = av.z; As[ar][ak + 3] = av.w;
        *(float4*)&Bs[bk][bc] = *(const float4*)(W + (k0 + bk) * 256 + n0 + bc);
        __syncthreads();
#pragma unroll
        for (int kk = 0; kk < 16; ++kk) {
            float a_[4], b_[4];
#pragma unroll
            for (int i = 0; i < 4; ++i) a_[i] = As[ty * 4 + i][kk];
            *(float4*)b_ = *(const float4*)&Bs[kk][tx * 4];
#pragma unroll
            for (int i = 0; i < 4; ++i)
#pragma unroll
                for (int j = 0; j < 4; ++j) acc[i][j] += a_[i] * b_[j];
        }
    }
#pragma unroll
    for (int i = 0; i < 4; ++i) {
        int row = m0 + ty * 4 + i;
#pragma unroll
        for (int j = 0; j < 4; ++j) {
            int col = n0 + tx * 4 + j;
            float v = gelu_tanh(acc[i][j] + bias[col]);
            _Float16 h1 = (_Float16)v;
            _Float16 h2 = (_Float16)(v - (float)h1);
            hs[row * 768 + col]       = __builtin_bit_cast(short, h1);
            hs[row * 768 + 256 + col] = __builtin_bit_cast(short, h2);
            hs[row * 768 + 512 + col] = __builtin_bit_cast(short, h1);
        }
    }
}

// ---------------- 128x128 MFMA GEMM, double-buffered global_load_lds ----------------
// EPI 1: +bias, tanh -> fused bilinear grid-sample, LDS-staged contiguous stores
// EPI 2: qkv scatter, fully LDS-staged: q panel / 8x4KB fragment-ordered K/V tiles
// EPI 3: fp32 split-K partial (blockIdx.y = ks)

template <int EPI>
__global__ __launch_bounds__(256, 2) void gemm128(
    const short* __restrict__ A, const short* __restrict__ BT,
    const float* __restrict__ b0, const float* __restrict__ b1, const float* __restrict__ b2,
    void* __restrict__ out0, void* __restrict__ out1, void* __restrict__ out2,
    int M, int N, int K, int lda, int ldb, const float* __restrict__ xsrc)
{
    __shared__ short lds[16384];          // 32 KB: 4 x 4096 (A0,A1,B0,B1)
    short* As0 = lds;
    short* As1 = lds + 4096;
    short* Bs0 = lds + 8192;
    short* Bs1 = lds + 12288;

    const int tid = threadIdx.x;
    const int lane = tid & 63, w = tid >> 6;
    const int rl = lane & 15, g = lane >> 4;
    const int wr = w >> 1, wc = w & 1;
    const int bid = blockIdx.x;
    int bm, bn;
    if (EPI == 1) {
        // XCD-sliced: each XCD owns 4 consecutive bn columns (nb=32, grid 512)
        bm = bid >> 5;
        bn = (bid & 7) * 4 + ((bid >> 3) & 3);
    } else if (EPI == 2) {
        // XCD-sliced: each XCD owns 16 consecutive bm panels (nb=6, grid 768)
        int s = bid >> 3;
        bm = (bid & 7) * 16 + s / 6;
        bn = s - (s / 6) * 6;
    } else {
        const int nb = N >> 7;
        bm = bid / nb;
        bn = bid % nb;
    }
    const int m0 = bm << 7, n0 = bn << 7;

    if (EPI == 3) { A += blockIdx.y << 8; BT += blockIdx.y << 8; }

    f32x4 acc[4][4];
#pragma unroll
    for (int m = 0; m < 4; ++m)
#pragma unroll
        for (int n = 0; n < 4; ++n) acc[m][n] = fzero();

    const short* ap = A + (long)(m0 + w * 32 + (lane >> 2)) * lda + ((lane & 3) << 3);
    const short* bp = BT + (long)(n0 + w * 32 + (lane >> 2)) * ldb + ((lane & 3) << 3);
    const int woff = w * 1024;

#define STAGE(dA, dB, kk) do { \
        gl16(ap + (kk), (dA) + woff); \
        gl16(ap + (kk) + 16 * lda, (dA) + woff + 512); \
        gl16(bp + (kk), (dB) + woff); \
        gl16(bp + (kk) + 16 * ldb, (dB) + woff + 512); } while (0)

    const int nt_ = K >> 5;
    STAGE(As0, Bs0, 0);
    __syncthreads();
    for (int t = 0; t < nt_; ++t) {
        const short* cA = (t & 1) ? As1 : As0;
        const short* cB = (t & 1) ? Bs1 : Bs0;
        short* nA = (t & 1) ? As0 : As1;
        short* nB = (t & 1) ? Bs0 : Bs1;
        if (t + 1 < nt_) STAGE(nA, nB, (t + 1) << 5);
        half8 af[4], bf[4];
#pragma unroll
        for (int m = 0; m < 4; ++m) af[m] = *(const half8*)&cA[(wr * 64 + m * 16 + rl) * 32 + g * 8];
#pragma unroll
        for (int n = 0; n < 4; ++n) bf[n] = *(const half8*)&cB[(wc * 64 + n * 16 + rl) * 32 + g * 8];
#pragma unroll
        for (int m = 0; m < 4; ++m)
#pragma unroll
            for (int n = 0; n < 4; ++n) acc[m][n] = MFMAH(af[m], bf[n], acc[m][n]);
        __syncthreads();
    }
#undef STAGE

    if (EPI == 1) {
        // sample into LDS tile [128][72] (stride 144B: 16B-aligned, bank-diagonal)
        const int d = n0 >> 9, c0 = (n0 >> 1) & 255;
#pragma unroll
        for (int m = 0; m < 4; ++m)
#pragma unroll
            for (int nt = 0; nt < 4; ++nt) {
                const int col = n0 + wc * 64 + nt * 16 + rl;
                float o4[4], po4[4];
                const float bb = b0[col];
#pragma unroll
                for (int j = 0; j < 4; ++j) o4[j] = tanhf(acc[m][nt][j] + bb);
#pragma unroll
                for (int j = 0; j < 4; ++j) po4[j] = __shfl_xor(o4[j], 1);
                const int jlo = (rl & 1) ? 2 : 0;
                const int cl = (wc * 64 + nt * 16 + rl) >> 1;
#pragma unroll
                for (int u = 0; u < 2; ++u) {
                    const int j = jlo + u;
                    float gx = (rl & 1) ? po4[j] : o4[j];
                    float gy = (rl & 1) ? o4[j] : po4[j];
                    gx = (gx + 1.f) * 127.5f;          // [0,255]
                    gy = (gy + 1.f) * 4095.5f;         // [0,8191]
                    float x0f = floorf(gx), y0f = floorf(gy);
                    float wx = gx - x0f, wy = gy - y0f;
                    int ix0 = (int)x0f, iy0 = (int)y0f;
                    int ix1 = min(ix0 + 1, 255), iy1 = min(iy0 + 1, 8191);
                    ix0 = max(min(ix0, 255), 0);
                    iy0 = max(min(iy0, 8191), 0);
                    ix1 = max(ix1, 0);
                    iy1 = max(iy1, 0);
                    const int rowl = wr * 64 + m * 16 + g * 4 + j;
                    const int b = (m0 + rowl) >> 10;
                    const float* xb = xsrc + b * 262144;
                    int r0 = (iy0 & 1023) << 8, r1 = (iy1 & 1023) << 8;
                    float v00 = xb[r0 + ix0], v01 = xb[r0 + ix1];
                    float v10 = xb[r1 + ix0], v11 = xb[r1 + ix1];
                    float r = v00 * (1.f - wy) * (1.f - wx) + v01 * (1.f - wy) * wx
                            + v10 * wy * (1.f - wx) + v11 * wy * wx;
                    lds[rowl * 72 + cl] = f2h(r);
                }
            }
        __syncthreads();
        // cooperative contiguous stores: 128 rows x 128B
        const int b = m0 >> 10, t0 = m0 & 1023;
        short* xo = (short*)out0 + ((long)(b * 8 + d) * 1024 + t0) * 256 + c0;
#pragma unroll
        for (int p = 0; p < 4; ++p) {
            int idx = p * 256 + tid, rowl = idx >> 3, ch = idx & 7;
            *(half8*)(xo + rowl * 256 + ch * 8) = *(const half8*)&lds[rowl * 72 + ch * 8];
        }
    } else if (EPI == 2) {
        // Stage the block's 128x128 output into LDS in FINAL layout, then
        // store fully-coalesced. bn 0-1: q panel. bn 2-3: K tiles. bn 4-5: V tiles.
#pragma unroll
        for (int m = 0; m < 4; ++m)
#pragma unroll
            for (int nt = 0; nt < 4; ++nt) {
                const int cl = wc * 64 + nt * 16 + rl;      // 0..127 within block
                const int col = n0 + cl;
#pragma unroll
                for (int j = 0; j < 4; ++j) {
                    const int tl = wr * 64 + m * 16 + g * 4 + j;   // 0..127
                    float v;
                    int slot;
                    if (bn < 2) {
                        v = (acc[m][nt][j] + b0[col]) * 0.18033688011112042f;  // 0.125*log2e
                        slot = tl * 128 + cl;
                    } else if (bn < 4) {
                        v = acc[m][nt][j] + b1[(bn - 2) * 128 + cl];
                        int hl = cl >> 6, dd = cl & 63;
                        int c = dd >> 4, hi2 = (dd >> 3) & 1, e = dd & 7;
                        int kkl = tl >> 5, l31t = tl & 31;
                        slot = (hl * 4 + kkl) * 2048 + (c * 64 + hi2 * 32 + l31t) * 8 + e;
                    } else {
                        v = acc[m][nt][j] + b2[(bn - 4) * 128 + cl];
                        int hl = cl >> 6, d = cl & 63;
                        int kkl = tl >> 5, chi = (tl >> 4) & 1, hi2 = (tl >> 3) & 1, e = tl & 7;
                        int c = chi * 2 + (d >> 5);
                        slot = (hl * 4 + kkl) * 2048 + (c * 64 + hi2 * 32 + (d & 31)) * 8 + e;
                    }
                    lds[slot] = f2h(v);
                }
            }
        __syncthreads();
        const int bh = m0 >> 10;
        if (bn < 2) {
            short* qo = (short*)out0 + (long)m0 * 256 + n0;
#pragma unroll
            for (int p = 0; p < 8; ++p) {
                int idx = p * 256 + tid, rowl = idx >> 4, ch = idx & 15;
                *(half8*)(qo + rowl * 256 + ch * 8) = *(const half8*)&lds[rowl * 128 + ch * 8];
            }
        } else {
            short* dst = (bn < 4) ? (short*)out1 : (short*)out2;
            const int hb = (bn < 4) ? (bn - 2) * 2 : (bn - 4) * 2;
            const int kk0 = (m0 & 1023) >> 5;
#pragma unroll
            for (int p = 0; p < 8; ++p) {
                int idx = p * 256 + tid, til = idx >> 8, wit = idx & 255;
                int hl = til >> 2, kkl = til & 3;
                long base = (((long)(bh * 4 + hb + hl) * 32) + kk0 + kkl) * 2048;
                *(half8*)(dst + base + wit * 8) = *(const half8*)&lds[til * 2048 + wit * 8];
            }
        }
    } else {  // EPI == 3: fp32 partial
        float* op = (float*)out0 + (long)blockIdx.y * M * N;
#pragma unroll
        for (int m = 0; m < 4; ++m)
#pragma unroll
            for (int nt = 0; nt < 4; ++nt) {
                const int col = n0 + wc * 64 + nt * 16 + rl;
#pragma unroll
                for (int j = 0; j < 4; ++j) {
                    const long grow = m0 + wr * 64 + m * 16 + g * 4 + j;
                    op[grow * N + col] = acc[m][nt][j];
                }
            }
    }
}

// sum split-K partials + bias -> fp32 out
__global__ void reduce_out_k(const float* __restrict__ p, const float* __restrict__ bo,
                             float* __restrict__ out) {
    int i = blockIdx.x * 256 + threadIdx.x;   // 524288
    float s = bo[i & 255];
#pragma unroll
    for (int ks = 0; ks < 8; ++ks) s += p[ks * 524288 + i];
    out[i] = s;
}

// ---------------- flash attention: LDS-staged coalesced K/V, swapped-operand ----------------

__global__ __launch_bounds__(256) void attn_k(const short* __restrict__ q, const short* __restrict__ kc,
                                              const short* __restrict__ vc, short* __restrict__ oc) {
    __shared__ short kv[8192];   // 16KB: buf b at b*4096 shorts: [K 2048 | V 2048]
    const int tid = threadIdx.x;
    const int lane = tid & 63, w = tid >> 6;
    const int l31 = lane & 31, hi = lane >> 5;
    const int bhh = blockIdx.x & 63;          // XCD-local: idx%8 = bhh%8
    const int bh = bhh >> 2, h = bhh & 3;
    const int q0 = (blockIdx.x >> 6) * 128 + w * 32;

    const short* qb = q + (long)bh * 262144 + h * 64;
    const short* kt = kc + (long)bhh * 65536;   // 32 tiles x 2048 shorts
    const short* vt = vc + (long)bhh * 65536;

    half8 qf[4];
#pragma unroll
    for (int c = 0; c < 4; ++c)
        qf[c] = *(const half8*)(qb + (long)(q0 + l31) * 256 + c * 16 + hi * 8);

    float m_ = -1e30f, l_ = 0.f;
    f32x16 O0, O1;
#pragma unroll
    for (int r = 0; r < 16; ++r) { O0[r] = 0.f; O1[r] = 0.f; }

    const int sw = w * 512 + lane * 8;        // per-lane src offset within a tile

#define KVSTAGE(kk, b) do { \
        gl16(kt + (kk) * 2048 + sw, &kv[(b) * 4096 + w * 512]); \
        gl16(vt + (kk) * 2048 + sw, &kv[(b) * 4096 + 2048 + w * 512]); } while (0)

    KVSTAGE(0, 0);
    __syncthreads();
    for (int kk = 0; kk < 32; ++kk) {
        const int b = kk & 1;
        if (kk + 1 < 32) KVSTAGE(kk + 1, b ^ 1);
        half8 KD[4], VD[4];
#pragma unroll
        for (int c = 0; c < 4; ++c) {
            KD[c] = *(const half8*)&kv[b * 4096 + c * 512 + lane * 8];
            VD[c] = *(const half8*)&kv[b * 4096 + 2048 + c * 512 + lane * 8];
        }
        f32x16 S;
#pragma unroll
        for (int r = 0; r < 16; ++r) S[r] = 0.f;
#pragma unroll
        for (int c = 0; c < 4; ++c) S = MFMA32(KD[c], qf[c], S);
        // tree max over 16, then cross-half via permlane32_swap
        float t8[8];
#pragma unroll
        for (int r = 0; r < 8; ++r) t8[r] = fmaxf(S[2 * r], S[2 * r + 1]);
        float mx = fmaxf(fmaxf(fmaxf(t8[0], t8[1]), fmaxf(t8[2], t8[3])),
                         fmaxf(fmaxf(t8[4], t8[5]), fmaxf(t8[6], t8[7])));
        uint2v sp = __builtin_amdgcn_permlane32_swap(f2u(mx), f2u(mx), false, false);
        mx = fmaxf(u2f(sp[0]), u2f(sp[1]));
        if (__any(mx > m_ + 8.f)) {           // defer-max THR=8 (log2 units)
            float mn = fmaxf(m_, mx);
            float sc = exp2f(m_ - mn);
            m_ = mn;
            l_ *= sc;
#pragma unroll
            for (int r = 0; r < 16; ++r) { O0[r] *= sc; O1[r] *= sc; }
        }
        float p[16];
#pragma unroll
        for (int r = 0; r < 16; ++r) p[r] = exp2f(S[r] - m_);
        float s8[8];
#pragma unroll
        for (int r = 0; r < 8; ++r) s8[r] = p[2 * r] + p[2 * r + 1];
        float rs = (((s8[0] + s8[1]) + (s8[2] + s8[3])) + ((s8[4] + s8[5]) + (s8[6] + s8[7])));
        uint2v sq = __builtin_amdgcn_permlane32_swap(f2u(rs), f2u(rs), false, false);
        rs = u2f(sq[0]) + u2f(sq[1]);
        l_ += rs;
        // pack P^T fragments (cvt_pkrtz + permlane32_swap)
        half8 PA[2];
#pragma unroll
        for (int c = 0; c < 2; ++c) {
            const int o = c * 8;
            unsigned a0 = f2u(__builtin_bit_cast(float, __builtin_amdgcn_cvt_pkrtz(p[o + 0], p[o + 1])));
            unsigned b0v = f2u(__builtin_bit_cast(float, __builtin_amdgcn_cvt_pkrtz(p[o + 4], p[o + 5])));
            unsigned a1 = f2u(__builtin_bit_cast(float, __builtin_amdgcn_cvt_pkrtz(p[o + 2], p[o + 3])));
            unsigned b1v = f2u(__builtin_bit_cast(float, __builtin_amdgcn_cvt_pkrtz(p[o + 6], p[o + 7])));
            uint2v r0 = __builtin_amdgcn_permlane32_swap(a0, b0v, false, false);
            uint2v r1 = __builtin_amdgcn_permlane32_swap(a1, b1v, false, false);
            uint4v wpk = {r0[0], r1[0], r0[1], r1[1]};
            PA[c] = __builtin_bit_cast(half8, wpk);
        }
        O0 = MFMA32(VD[0], PA[0], O0);
        O1 = MFMA32(VD[1], PA[0], O1);
        O0 = MFMA32(VD[2], PA[1], O0);
        O1 = MFMA32(VD[3], PA[1], O1);
        __syncthreads();
    }
#undef KVSTAGE

    const float inv = 1.f / l_;
    const int b = bh >> 3, d = bh & 7;
    const int t = q0 + l31;
    short* ob = oc + ((long)(b * 1024 + t) * 8 + d) * 256 + h * 64;
#pragma unroll
    for (int rr = 0; rr < 8; ++rr) {
        int dvb = (rr & 1) * 2 + 8 * (rr >> 1) + 4 * hi;
        unsigned u0 = (unsigned short)f2h(O0[2 * rr] * inv) | ((unsigned)(unsigned short)f2h(O0[2 * rr + 1] * inv) << 16);
        unsigned u1 = (unsigned short)f2h(O1[2 * rr] * inv) | ((unsigned)(unsigned short)f2h(O1[2 * rr + 1] * inv) << 16);
        *(unsigned*)(ob + dvb) = u0;
        *(unsigned*)(ob + 32 + dvb) = u1;
    }
}

// ---------------- launch ----------------

extern "C" void kernel_launch(void* const* d_in, const int* in_sizes, int n_in,
                              void* d_out, int out_size, void* d_ws, size_t ws_size,
                              hipStream_t stream) {
    const float* x     = (const float*)d_in[0];
    const float* Woff1 = (const float*)d_in[1];
    const float* boff1 = (const float*)d_in[2];
    const float* Woff2 = (const float*)d_in[3];
    const float* boff2 = (const float*)d_in[4];
    const float* Wq    = (const float*)d_in[5];
    const float* bq    = (const float*)d_in[6];
    const float* Wk    = (const float*)d_in[7];
    const float* bk    = (const float*)d_in[8];
    const float* Wv    = (const float*)d_in[9];
    const float* bv    = (const float*)d_in[10];
    const float* Wo    = (const float*)d_in[11];
    const float* bo    = (const float*)d_in[12];

    char* ws = (char*)d_ws;
    short* hsplit = (short*)(ws + 0);             // 2048*768*2  = 3,145,728
    short* B2T    = (short*)(ws + 3145728);       // 4096*768*2  = 6,291,456 (end 9,437,184)
    short* cat    = (short*)(ws + 0);             // 2048*2048*2 = 8,388,608 (alias; B2T/hsplit dead)
    short* Wtqkv  = (short*)(ws + 9437184);       // 768*256*2   =   393,216
    short* WtoT   = (short*)(ws + 9830400);       // 256*2048*2  = 1,048,576
    short* xs     = (short*)(ws + 10878976);      // 16384*256*2 = 8,388,608
    short* qbuf   = (short*)(ws + 19267584);      // 8,388,608
    short* kcoal  = (short*)(ws + 27656192);      // 8,388,608 (64 bhh x 32 tiles x 4KB)
    short* vcoal  = (short*)(ws + 36044800);      // 8,388,608  (end 44,433,408)
    float* parts  = (float*)(ws + 44433408);      // 8*2048*256*4 = 16,777,216 (end 61,210,624)

    // prep
    split_w2_k<<<256, 256, 0, stream>>>(Woff2, B2T);
    qkv_prep_k<<<768, 256, 0, stream>>>(Wq, Wk, Wv, Wtqkv);
    wo_prep_k<<<2048, 256, 0, stream>>>(Wo, WtoT);

    // offset network stage 1: exact fp32 + gelu + fp16 split
    gemm1_k<<<128, 256, 0, stream>>>(x, Woff1, boff1, hsplit);

    // stage 2 (f16 3-term) + fused tanh + bilinear resampling
    gemm128<1><<<(2048 / 128) * (4096 / 128), 256, 0, stream>>>(
        hsplit, B2T, boff2, nullptr, nullptr, xs, nullptr, nullptr, 2048, 4096, 768, 768, 768, x);

    // qkv projections (q pre-scaled into exp2 domain; K/V fragment-ordered, LDS-staged stores)
    gemm128<2><<<(16384 / 128) * (768 / 128), 256, 0, stream>>>(
        xs, Wtqkv, bq, bk, bv, qbuf, kcoal, vcoal, 16384, 768, 256, 256, 256, nullptr);

    // attention (LDS-staged coalesced K/V, swapped-operand)
    attn_k<<<512, 256, 0, stream>>>(qbuf, kcoal, vcoal, cat);

    // output projection: split-K=8 partials + reduce
    gemm128<3><<<dim3((2048 / 128) * (256 / 128), 8), 256, 0, stream>>>(
        cat, WtoT, nullptr, nullptr, nullptr, parts, nullptr, nullptr, 2048, 256, 256, 2048, 2048, nullptr);
    reduce_out_k<<<2048, 256, 0, stream>>>(parts, bo, (float*)d_out);
}

// Round 10
// 155.871 us; speedup vs baseline: 1.8493x; 1.0585x over previous
//
#include <hip/hip_runtime.h>
#include <hip/hip_bf16.h>

typedef __attribute__((ext_vector_type(8))) _Float16 half8;   // 8 f16 = 4 VGPRs
typedef __attribute__((ext_vector_type(4))) float f32x4;
typedef __attribute__((ext_vector_type(16))) float f32x16;
typedef __attribute__((ext_vector_type(2))) unsigned uint2v;
typedef __attribute__((ext_vector_type(4))) unsigned uint4v;
typedef __attribute__((ext_vector_type(2), aligned(4))) float f32x2a;  // 4B-aligned float2

#define MFMAH(a, b, c) __builtin_amdgcn_mfma_f32_16x16x32_f16((a), (b), (c), 0, 0, 0)
#define MFMA32(a, b, c) __builtin_amdgcn_mfma_f32_32x32x16_f16((a), (b), (c), 0, 0, 0)

__device__ __forceinline__ short f2h(float v) { _Float16 h = (_Float16)v; return __builtin_bit_cast(short, h); }
__device__ __forceinline__ f32x4 fzero() { f32x4 z = {0.f, 0.f, 0.f, 0.f}; return z; }
__device__ __forceinline__ float u2f(unsigned u) { return __builtin_bit_cast(float, u); }
__device__ __forceinline__ unsigned f2u(float f) { return __builtin_bit_cast(unsigned, f); }

__device__ __forceinline__ void gl16(const void* g, void* l) {
    // async global->LDS, 16B/lane; LDS dest = wave-uniform base + lane*16
    __builtin_amdgcn_global_load_lds((const __attribute__((address_space(1))) unsigned*)g,
                                     (__attribute__((address_space(3))) unsigned*)l, 16, 0, 0);
}

__device__ __forceinline__ float fast_tanh(float z) {
    // 1 - 2/(e^2z + 1): exact saturation at +-inf, err ~1e-6 (v_exp based)
    float E = __expf(2.f * z);
    return 1.f - 2.f / (E + 1.f);
}

__device__ __forceinline__ float gelu_tanh(float v) {
    float u = 0.7978845608028654f * (v + 0.044715f * v * v * v);
    return 0.5f * v * (1.f + fast_tanh(u));
}

// ---------------- prep kernels ----------------

// W_off2 (256,4096) -> B2T (4096,768) f16 [w1|w1|w2], LDS-tiled transpose
__global__ __launch_bounds__(256) void split_w2_k(const float* __restrict__ w, short* __restrict__ dst) {
    __shared__ float t[64][65];
    const int tid = threadIdx.x;
    const int bk = blockIdx.x >> 6, bn = blockIdx.x & 63;    // 4 x 64 blocks
    const int k0 = bk * 64, n0 = bn * 64;
#pragma unroll
    for (int p = 0; p < 16; ++p) {
        int idx = p * 256 + tid, r = idx >> 6, c = idx & 63;
        t[r][c] = w[(long)(k0 + r) * 4096 + n0 + c];
    }
    __syncthreads();
#pragma unroll
    for (int p = 0; p < 16; ++p) {
        int idx = p * 256 + tid, nr = idx >> 6, kc = idx & 63;
        float v = t[kc][nr];
        _Float16 w1 = (_Float16)v;
        _Float16 w2 = (_Float16)(v - (float)w1);
        long base = (long)(n0 + nr) * 768 + k0 + kc;
        dst[base]       = __builtin_bit_cast(short, w1);
        dst[base + 256] = __builtin_bit_cast(short, w1);
        dst[base + 512] = __builtin_bit_cast(short, w2);
    }
}

__global__ void qkv_prep_k(const float* __restrict__ Wq, const float* __restrict__ Wk,
                           const float* __restrict__ Wv, short* __restrict__ dst) {
    int i = blockIdx.x * 256 + threadIdx.x;        // 768*256
    int n = i >> 8, k = i & 255;
    const float* s = (n < 256) ? Wq : (n < 512) ? Wk : Wv;
    dst[i] = f2h(s[k * 256 + (n & 255)]);
}

__global__ void wo_prep_k(const float* __restrict__ Wo, short* __restrict__ dst) {
    int i = blockIdx.x * 256 + threadIdx.x;        // 256*2048
    int n = i >> 11, k = i & 2047;
    dst[i] = f2h(Wo[k * 256 + n]);
}

// ---------------- GEMM1: exact fp32, fused gelu + fp16 hi/lo split ----------------

__global__ __launch_bounds__(256) void gemm1_k(const float* __restrict__ x, const float* __restrict__ W,
                                               const float* __restrict__ bias, short* __restrict__ hs) {
    __shared__ float As[64][17];
    __shared__ float Bs[16][68];
    const int tid = threadIdx.x;
    const int bm = blockIdx.x >> 2, bn = blockIdx.x & 3;     // 32 x 4
    const int m0 = bm * 64, n0 = bn * 64;
    const int ty = tid >> 4, tx = tid & 15;
    float acc[4][4] = {};
    const int ar = tid >> 2, ak = (tid & 3) << 2;
    const int bk = tid >> 4, bc = (tid & 15) << 2;

    for (int k0 = 0; k0 < 256; k0 += 16) {
        __syncthreads();
        float4 av = *(const float4*)(x + (m0 + ar) * 256 + k0 + ak);
        As[ar][ak + 0] = av.x; As[ar][ak + 1] = av.y; As[ar][ak + 2] = av.z; As[ar][ak + 3] = av.w;
        *(float4*)&Bs[bk][bc] = *(const float4*)(W + (k0 + bk) * 256 + n0 + bc);
        __syncthreads();
#pragma unroll
        for (int kk = 0; kk < 16; ++kk) {
            float a_[4], b_[4];
#pragma unroll
            for (int i = 0; i < 4; ++i) a_[i] = As[ty * 4 + i][kk];
            *(float4*)b_ = *(const float4*)&Bs[kk][tx * 4];
#pragma unroll
            for (int i = 0; i < 4; ++i)
#pragma unroll
                for (int j = 0; j < 4; ++j) acc[i][j] += a_[i] * b_[j];
        }
    }
#pragma unroll
    for (int i = 0; i < 4; ++i) {
        int row = m0 + ty * 4 + i;
#pragma unroll
        for (int j = 0; j < 4; ++j) {
            int col = n0 + tx * 4 + j;
            float v = gelu_tanh(acc[i][j] + bias[col]);
            _Float16 h1 = (_Float16)v;
            _Float16 h2 = (_Float16)(v - (float)h1);
            hs[row * 768 + col]       = __builtin_bit_cast(short, h1);
            hs[row * 768 + 256 + col] = __builtin_bit_cast(short, h2);
            hs[row * 768 + 512 + col] = __builtin_bit_cast(short, h1);
        }
    }
}

// ---------------- 128x128 MFMA GEMM, counted-vmcnt double-buffered staging ----------------
// T4 schedule: STAGE(next); s_waitcnt vmcnt(4); s_barrier; ds_read+MFMA(cur); s_barrier.
// Prefetched loads stay in flight across barriers (never drained to 0 mid-loop).
// EPI 1: +bias, fast-tanh -> fused bilinear grid-sample (float2-merged gathers)
// EPI 2: qkv scatter, LDS-staged final layouts
// EPI 3: fp32 split-K partial (blockIdx.y = ks)

template <int EPI>
__global__ __launch_bounds__(256, 2) void gemm128(
    const short* __restrict__ A, const short* __restrict__ BT,
    const float* __restrict__ b0, const float* __restrict__ b1, const float* __restrict__ b2,
    void* __restrict__ out0, void* __restrict__ out1, void* __restrict__ out2,
    int M, int N, int K, int lda, int ldb, const float* __restrict__ xsrc)
{
    __shared__ short lds[16384];          // 32 KB: 4 x 4096 (A0,A1,B0,B1)
    short* As0 = lds;
    short* As1 = lds + 4096;
    short* Bs0 = lds + 8192;
    short* Bs1 = lds + 12288;

    const int tid = threadIdx.x;
    const int lane = tid & 63, w = tid >> 6;
    const int rl = lane & 15, g = lane >> 4;
    const int wr = w >> 1, wc = w & 1;
    const int bid = blockIdx.x;
    int bm, bn;
    if (EPI == 1) {
        bm = bid >> 5;
        bn = (bid & 7) * 4 + ((bid >> 3) & 3);
    } else if (EPI == 2) {
        int s = bid >> 3;
        bm = (bid & 7) * 16 + s / 6;
        bn = s - (s / 6) * 6;
    } else {
        const int nb = N >> 7;
        bm = bid / nb;
        bn = bid % nb;
    }
    const int m0 = bm << 7, n0 = bn << 7;

    if (EPI == 3) { A += blockIdx.y << 8; BT += blockIdx.y << 8; }

    f32x4 acc[4][4];
#pragma unroll
    for (int m = 0; m < 4; ++m)
#pragma unroll
        for (int n = 0; n < 4; ++n) acc[m][n] = fzero();

    const short* ap = A + (long)(m0 + w * 32 + (lane >> 2)) * lda + ((lane & 3) << 3);
    const short* bp = BT + (long)(n0 + w * 32 + (lane >> 2)) * ldb + ((lane & 3) << 3);
    const int woff = w * 1024;

#define STAGE(dA, dB, kk) do { \
        gl16(ap + (kk), (dA) + woff); \
        gl16(ap + (kk) + 16 * lda, (dA) + woff + 512); \
        gl16(bp + (kk), (dB) + woff); \
        gl16(bp + (kk) + 16 * ldb, (dB) + woff + 512); } while (0)

    const int nt_ = K >> 5;
    STAGE(As0, Bs0, 0);
    for (int t = 0; t < nt_; ++t) {
        const short* cA = (t & 1) ? As1 : As0;
        const short* cB = (t & 1) ? Bs1 : Bs0;
        short* nA = (t & 1) ? As0 : As1;
        short* nB = (t & 1) ? Bs0 : Bs1;
        if (t + 1 < nt_) {
            STAGE(nA, nB, (t + 1) << 5);
            asm volatile("s_waitcnt vmcnt(4)" ::: "memory");   // cur's 4 loads landed
        } else {
            asm volatile("s_waitcnt vmcnt(0)" ::: "memory");
        }
        __builtin_amdgcn_s_barrier();                           // all waves' cur landed
        half8 af[4], bf[4];
#pragma unroll
        for (int m = 0; m < 4; ++m) af[m] = *(const half8*)&cA[(wr * 64 + m * 16 + rl) * 32 + g * 8];
#pragma unroll
        for (int n = 0; n < 4; ++n) bf[n] = *(const half8*)&cB[(wc * 64 + n * 16 + rl) * 32 + g * 8];
#pragma unroll
        for (int m = 0; m < 4; ++m)
#pragma unroll
            for (int n = 0; n < 4; ++n) acc[m][n] = MFMAH(af[m], bf[n], acc[m][n]);
        __builtin_amdgcn_s_barrier();                           // reads done before overwrite
    }
#undef STAGE

    if (EPI == 1) {
        // sample into LDS tile [128][72] (stride 144B: 16B-aligned, bank-diagonal)
        const int d = n0 >> 9, c0 = (n0 >> 1) & 255;
#pragma unroll
        for (int m = 0; m < 4; ++m)
#pragma unroll
            for (int nt = 0; nt < 4; ++nt) {
                const int col = n0 + wc * 64 + nt * 16 + rl;
                float o4[4], po4[4];
                const float bb = b0[col];
#pragma unroll
                for (int j = 0; j < 4; ++j) o4[j] = fast_tanh(acc[m][nt][j] + bb);
#pragma unroll
                for (int j = 0; j < 4; ++j) po4[j] = __shfl_xor(o4[j], 1);
                const int jlo = (rl & 1) ? 2 : 0;
                const int cl = (wc * 64 + nt * 16 + rl) >> 1;
#pragma unroll
                for (int u = 0; u < 2; ++u) {
                    const int j = jlo + u;
                    float gx = (rl & 1) ? po4[j] : o4[j];
                    float gy = (rl & 1) ? o4[j] : po4[j];
                    gx = (gx + 1.f) * 127.5f;          // [0,255]
                    gy = (gy + 1.f) * 4095.5f;         // [0,8191]
                    float x0f = floorf(gx), y0f = floorf(gy);
                    float wx = gx - x0f, wy = gy - y0f;
                    int ix0 = (int)x0f, iy0 = (int)y0f;
                    int iy1 = min(iy0 + 1, 8191);
                    iy0 = max(min(iy0, 8191), 0);
                    iy1 = max(iy1, 0);
                    int ixc = max(min(ix0, 254), 0);
                    const int rowl = wr * 64 + m * 16 + g * 4 + j;
                    const int b = (m0 + rowl) >> 10;
                    const float* xb = xsrc + b * 262144;
                    int r0 = (iy0 & 1023) << 8, r1 = (iy1 & 1023) << 8;
                    // merged pair-loads: x[ixc], x[ixc+1] cover both clamped taps
                    f32x2a fx0 = *(const f32x2a*)(xb + r0 + ixc);
                    f32x2a fx1 = *(const f32x2a*)(xb + r1 + ixc);
                    float v00 = (ix0 >= 255) ? fx0[1] : fx0[0];
                    float v01 = (ix0 < 0)    ? fx0[0] : fx0[1];
                    float v10 = (ix0 >= 255) ? fx1[1] : fx1[0];
                    float v11 = (ix0 < 0)    ? fx1[0] : fx1[1];
                    float r = v00 * (1.f - wy) * (1.f - wx) + v01 * (1.f - wy) * wx
                            + v10 * wy * (1.f - wx) + v11 * wy * wx;
                    lds[rowl * 72 + cl] = f2h(r);
                }
            }
        __syncthreads();
        // cooperative contiguous stores: 128 rows x 128B
        const int b = m0 >> 10, t0 = m0 & 1023;
        short* xo = (short*)out0 + ((long)(b * 8 + d) * 1024 + t0) * 256 + c0;
#pragma unroll
        for (int p = 0; p < 4; ++p) {
            int idx = p * 256 + tid, rowl = idx >> 3, ch = idx & 7;
            *(half8*)(xo + rowl * 256 + ch * 8) = *(const half8*)&lds[rowl * 72 + ch * 8];
        }
    } else if (EPI == 2) {
        // Stage the block's 128x128 output into LDS in FINAL layout, then
        // store fully-coalesced. bn 0-1: q panel. bn 2-3: K tiles. bn 4-5: V tiles.
#pragma unroll
        for (int m = 0; m < 4; ++m)
#pragma unroll
            for (int nt = 0; nt < 4; ++nt) {
                const int cl = wc * 64 + nt * 16 + rl;      // 0..127 within block
                const int col = n0 + cl;
#pragma unroll
                for (int j = 0; j < 4; ++j) {
                    const int tl = wr * 64 + m * 16 + g * 4 + j;   // 0..127
                    float v;
                    int slot;
                    if (bn < 2) {
                        v = (acc[m][nt][j] + b0[col]) * 0.18033688011112042f;  // 0.125*log2e
                        slot = tl * 128 + cl;
                    } else if (bn < 4) {
                        v = acc[m][nt][j] + b1[(bn - 2) * 128 + cl];
                        int hl = cl >> 6, dd = cl & 63;
                        int c = dd >> 4, hi2 = (dd >> 3) & 1, e = dd & 7;
                        int kkl = tl >> 5, l31t = tl & 31;
                        slot = (hl * 4 + kkl) * 2048 + (c * 64 + hi2 * 32 + l31t) * 8 + e;
                    } else {
                        v = acc[m][nt][j] + b2[(bn - 4) * 128 + cl];
                        int hl = cl >> 6, d = cl & 63;
                        int kkl = tl >> 5, chi = (tl >> 4) & 1, hi2 = (tl >> 3) & 1, e = tl & 7;
                        int c = chi * 2 + (d >> 5);
                        slot = (hl * 4 + kkl) * 2048 + (c * 64 + hi2 * 32 + (d & 31)) * 8 + e;
                    }
                    lds[slot] = f2h(v);
                }
            }
        __syncthreads();
        const int bh = m0 >> 10;
        if (bn < 2) {
            short* qo = (short*)out0 + (long)m0 * 256 + n0;
#pragma unroll
            for (int p = 0; p < 8; ++p) {
                int idx = p * 256 + tid, rowl = idx >> 4, ch = idx & 15;
                *(half8*)(qo + rowl * 256 + ch * 8) = *(const half8*)&lds[rowl * 128 + ch * 8];
            }
        } else {
            short* dst = (bn < 4) ? (short*)out1 : (short*)out2;
            const int hb = (bn < 4) ? (bn - 2) * 2 : (bn - 4) * 2;
            const int kk0 = (m0 & 1023) >> 5;
#pragma unroll
            for (int p = 0; p < 8; ++p) {
                int idx = p * 256 + tid, til = idx >> 8, wit = idx & 255;
                int hl = til >> 2, kkl = til & 3;
                long base = (((long)(bh * 4 + hb + hl) * 32) + kk0 + kkl) * 2048;
                *(half8*)(dst + base + wit * 8) = *(const half8*)&lds[til * 2048 + wit * 8];
            }
        }
    } else {  // EPI == 3: fp32 partial
        float* op = (float*)out0 + (long)blockIdx.y * M * N;
#pragma unroll
        for (int m = 0; m < 4; ++m)
#pragma unroll
            for (int nt = 0; nt < 4; ++nt) {
                const int col = n0 + wc * 64 + nt * 16 + rl;
#pragma unroll
                for (int j = 0; j < 4; ++j) {
                    const long grow = m0 + wr * 64 + m * 16 + g * 4 + j;
                    op[grow * N + col] = acc[m][nt][j];
                }
            }
    }
}

// sum split-K partials + bias -> fp32 out
__global__ void reduce_out_k(const float* __restrict__ p, const float* __restrict__ bo,
                             float* __restrict__ out) {
    int i = blockIdx.x * 256 + threadIdx.x;   // 524288
    float s = bo[i & 255];
#pragma unroll
    for (int ks = 0; ks < 8; ++ks) s += p[ks * 524288 + i];
    out[i] = s;
}

// ---------------- flash attention: LDS-staged coalesced K/V, swapped-operand ----------------

__global__ __launch_bounds__(256) void attn_k(const short* __restrict__ q, const short* __restrict__ kc,
                                              const short* __restrict__ vc, short* __restrict__ oc) {
    __shared__ short kv[8192];   // 16KB: buf b at b*4096 shorts: [K 2048 | V 2048]
    const int tid = threadIdx.x;
    const int lane = tid & 63, w = tid >> 6;
    const int l31 = lane & 31, hi = lane >> 5;
    const int bhh = blockIdx.x & 63;          // XCD-local: idx%8 = bhh%8
    const int bh = bhh >> 2, h = bhh & 3;
    const int q0 = (blockIdx.x >> 6) * 128 + w * 32;

    const short* qb = q + (long)bh * 262144 + h * 64;
    const short* kt = kc + (long)bhh * 65536;   // 32 tiles x 2048 shorts
    const short* vt = vc + (long)bhh * 65536;

    half8 qf[4];
#pragma unroll
    for (int c = 0; c < 4; ++c)
        qf[c] = *(const half8*)(qb + (long)(q0 + l31) * 256 + c * 16 + hi * 8);

    float m_ = -1e30f, l_ = 0.f;
    f32x16 O0, O1;
#pragma unroll
    for (int r = 0; r < 16; ++r) { O0[r] = 0.f; O1[r] = 0.f; }

    const int sw = w * 512 + lane * 8;        // per-lane src offset within a tile

#define KVSTAGE(kk, b) do { \
        gl16(kt + (kk) * 2048 + sw, &kv[(b) * 4096 + w * 512]); \
        gl16(vt + (kk) * 2048 + sw, &kv[(b) * 4096 + 2048 + w * 512]); } while (0)

    KVSTAGE(0, 0);
    __syncthreads();
    for (int kk = 0; kk < 32; ++kk) {
        const int b = kk & 1;
        if (kk + 1 < 32) KVSTAGE(kk + 1, b ^ 1);
        half8 KD[4], VD[4];
#pragma unroll
        for (int c = 0; c < 4; ++c) {
            KD[c] = *(const half8*)&kv[b * 4096 + c * 512 + lane * 8];
            VD[c] = *(const half8*)&kv[b * 4096 + 2048 + c * 512 + lane * 8];
        }
        f32x16 S;
#pragma unroll
        for (int r = 0; r < 16; ++r) S[r] = 0.f;
#pragma unroll
        for (int c = 0; c < 4; ++c) S = MFMA32(KD[c], qf[c], S);
        // tree max over 16, then cross-half via permlane32_swap
        float t8[8];
#pragma unroll
        for (int r = 0; r < 8; ++r) t8[r] = fmaxf(S[2 * r], S[2 * r + 1]);
        float mx = fmaxf(fmaxf(fmaxf(t8[0], t8[1]), fmaxf(t8[2], t8[3])),
                         fmaxf(fmaxf(t8[4], t8[5]), fmaxf(t8[6], t8[7])));
        uint2v sp = __builtin_amdgcn_permlane32_swap(f2u(mx), f2u(mx), false, false);
        mx = fmaxf(u2f(sp[0]), u2f(sp[1]));
        if (__any(mx > m_ + 8.f)) {           // defer-max THR=8 (log2 units)
            float mn = fmaxf(m_, mx);
            float sc = exp2f(m_ - mn);
            m_ = mn;
            l_ *= sc;
#pragma unroll
            for (int r = 0; r < 16; ++r) { O0[r] *= sc; O1[r] *= sc; }
        }
        float p[16];
#pragma unroll
        for (int r = 0; r < 16; ++r) p[r] = exp2f(S[r] - m_);
        float s8[8];
#pragma unroll
        for (int r = 0; r < 8; ++r) s8[r] = p[2 * r] + p[2 * r + 1];
        float rs = (((s8[0] + s8[1]) + (s8[2] + s8[3])) + ((s8[4] + s8[5]) + (s8[6] + s8[7])));
        uint2v sq = __builtin_amdgcn_permlane32_swap(f2u(rs), f2u(rs), false, false);
        rs = u2f(sq[0]) + u2f(sq[1]);
        l_ += rs;
        // pack P^T fragments (cvt_pkrtz + permlane32_swap)
        half8 PA[2];
#pragma unroll
        for (int c = 0; c < 2; ++c) {
            const int o = c * 8;
            unsigned a0 = f2u(__builtin_bit_cast(float, __builtin_amdgcn_cvt_pkrtz(p[o + 0], p[o + 1])));
            unsigned b0v = f2u(__builtin_bit_cast(float, __builtin_amdgcn_cvt_pkrtz(p[o + 4], p[o + 5])));
            unsigned a1 = f2u(__builtin_bit_cast(float, __builtin_amdgcn_cvt_pkrtz(p[o + 2], p[o + 3])));
            unsigned b1v = f2u(__builtin_bit_cast(float, __builtin_amdgcn_cvt_pkrtz(p[o + 6], p[o + 7])));
            uint2v r0 = __builtin_amdgcn_permlane32_swap(a0, b0v, false, false);
            uint2v r1 = __builtin_amdgcn_permlane32_swap(a1, b1v, false, false);
            uint4v wpk = {r0[0], r1[0], r0[1], r1[1]};
            PA[c] = __builtin_bit_cast(half8, wpk);
        }
        O0 = MFMA32(VD[0], PA[0], O0);
        O1 = MFMA32(VD[1], PA[0], O1);
        O0 = MFMA32(VD[2], PA[1], O0);
        O1 = MFMA32(VD[3], PA[1], O1);
        __syncthreads();
    }
#undef KVSTAGE

    const float inv = 1.f / l_;
    const int b = bh >> 3, d = bh & 7;
    const int t = q0 + l31;
    short* ob = oc + ((long)(b * 1024 + t) * 8 + d) * 256 + h * 64;
#pragma unroll
    for (int rr = 0; rr < 8; ++rr) {
        int dvb = (rr & 1) * 2 + 8 * (rr >> 1) + 4 * hi;
        unsigned u0 = (unsigned short)f2h(O0[2 * rr] * inv) | ((unsigned)(unsigned short)f2h(O0[2 * rr + 1] * inv) << 16);
        unsigned u1 = (unsigned short)f2h(O1[2 * rr] * inv) | ((unsigned)(unsigned short)f2h(O1[2 * rr + 1] * inv) << 16);
        *(unsigned*)(ob + dvb) = u0;
        *(unsigned*)(ob + 32 + dvb) = u1;
    }
}

// ---------------- launch ----------------

extern "C" void kernel_launch(void* const* d_in, const int* in_sizes, int n_in,
                              void* d_out, int out_size, void* d_ws, size_t ws_size,
                              hipStream_t stream) {
    const float* x     = (const float*)d_in[0];
    const float* Woff1 = (const float*)d_in[1];
    const float* boff1 = (const float*)d_in[2];
    const float* Woff2 = (const float*)d_in[3];
    const float* boff2 = (const float*)d_in[4];
    const float* Wq    = (const float*)d_in[5];
    const float* bq    = (const float*)d_in[6];
    const float* Wk    = (const float*)d_in[7];
    const float* bk    = (const float*)d_in[8];
    const float* Wv    = (const float*)d_in[9];
    const float* bv    = (const float*)d_in[10];
    const float* Wo    = (const float*)d_in[11];
    const float* bo    = (const float*)d_in[12];

    char* ws = (char*)d_ws;
    short* hsplit = (short*)(ws + 0);             // 2048*768*2  = 3,145,728
    short* B2T    = (short*)(ws + 3145728);       // 4096*768*2  = 6,291,456 (end 9,437,184)
    short* cat    = (short*)(ws + 0);             // 2048*2048*2 = 8,388,608 (alias; B2T/hsplit dead)
    short* Wtqkv  = (short*)(ws + 9437184);       // 768*256*2   =   393,216
    short* WtoT   = (short*)(ws + 9830400);       // 256*2048*2  = 1,048,576
    short* xs     = (short*)(ws + 10878976);      // 16384*256*2 = 8,388,608
    short* qbuf   = (short*)(ws + 19267584);      // 8,388,608
    short* kcoal  = (short*)(ws + 27656192);      // 8,388,608 (64 bhh x 32 tiles x 4KB)
    short* vcoal  = (short*)(ws + 36044800);      // 8,388,608  (end 44,433,408)
    float* parts  = (float*)(ws + 44433408);      // 8*2048*256*4 = 16,777,216 (end 61,210,624)

    // prep
    split_w2_k<<<256, 256, 0, stream>>>(Woff2, B2T);
    qkv_prep_k<<<768, 256, 0, stream>>>(Wq, Wk, Wv, Wtqkv);
    wo_prep_k<<<2048, 256, 0, stream>>>(Wo, WtoT);

    // offset network stage 1: exact fp32 + gelu + fp16 split
    gemm1_k<<<128, 256, 0, stream>>>(x, Woff1, boff1, hsplit);

    // stage 2 (f16 3-term) + fused tanh + bilinear resampling
    gemm128<1><<<(2048 / 128) * (4096 / 128), 256, 0, stream>>>(
        hsplit, B2T, boff2, nullptr, nullptr, xs, nullptr, nullptr, 2048, 4096, 768, 768, 768, x);

    // qkv projections (q pre-scaled into exp2 domain; K/V fragment-ordered, LDS-staged stores)
    gemm128<2><<<(16384 / 128) * (768 / 128), 256, 0, stream>>>(
        xs, Wtqkv, bq, bk, bv, qbuf, kcoal, vcoal, 16384, 768, 256, 256, 256, nullptr);

    // attention (LDS-staged coalesced K/V, swapped-operand)
    attn_k<<<512, 256, 0, stream>>>(qbuf, kcoal, vcoal, cat);

    // output projection: split-K=8 partials + reduce
    gemm128<3><<<dim3((2048 / 128) * (256 / 128), 8), 256, 0, stream>>>(
        cat, WtoT, nullptr, nullptr, nullptr, parts, nullptr, nullptr, 2048, 256, 256, 2048, 2048, nullptr);
    reduce_out_k<<<2048, 256, 0, stream>>>(parts, bo, (float*)d_out);
}